// Round 2
// baseline (1942.926 us; speedup 1.0000x reference)
//
#include <hip/hip_runtime.h>
#include <hip/hip_bf16.h>

#define H 256
#define LN_EPS 1e-5f
#define PITCH 264   // bf16 elements per LDS A-row (256 + 8 pad), 528 B
#define ELP 260     // f32 elements per LDS el-row (256 + 4 pad)
#define TE 64       // edges per tile (edge kernel)

typedef __attribute__((ext_vector_type(8))) short bf16x8;   // 8 bf16 = 4 VGPRs
typedef __attribute__((ext_vector_type(4))) float f32x4;    // MFMA 16x16 accum

// ---------- helpers ----------
__device__ __forceinline__ float bf2f(unsigned short u) {
  union { unsigned int i; float f; } v; v.i = ((unsigned int)u) << 16; return v.f;
}
__device__ __forceinline__ unsigned short f2bf(float f) {
  union { float f; unsigned int i; } v; v.f = f;
  unsigned int x = v.i;
  return (unsigned short)((x + 0x7fffu + ((x >> 16) & 1u)) >> 16);  // RNE
}
__device__ __forceinline__ void fsplit(float v, unsigned short& hi, unsigned short& lo) {
  hi = f2bf(v);
  lo = f2bf(v - bf2f(hi));
}

// fp32 register-tiled GEMM core (precompute only)
__device__ __forceinline__ void gemm_tile(const float* __restrict__ sA,
                                          const float* __restrict__ W,
                                          int lane_j, int rg, float acc[8][4]) {
#pragma unroll
  for (int mm = 0; mm < 8; mm++)
#pragma unroll
    for (int cc = 0; cc < 4; cc++) acc[mm][cc] = 0.f;
  for (int k = 0; k < H; k += 4) {
    float tvf[8][4];
#pragma unroll
    for (int mm = 0; mm < 8; mm++)
      *(float4*)&tvf[mm][0] = *(const float4*)&sA[(rg * 8 + mm) * H + k];
#pragma unroll
    for (int kk = 0; kk < 4; kk++) {
      const float* wr = W + (k + kk) * H + lane_j;
      float w0 = wr[0], w1 = wr[64], w2 = wr[128], w3 = wr[192];
#pragma unroll
      for (int mm = 0; mm < 8; mm++) {
        float av = tvf[mm][kk];
        acc[mm][0] = fmaf(av, w0, acc[mm][0]);
        acc[mm][1] = fmaf(av, w1, acc[mm][1]);
        acc[mm][2] = fmaf(av, w2, acc[mm][2]);
        acc[mm][3] = fmaf(av, w3, acc[mm][3]);
      }
    }
  }
}

// ---------- precompute kernels ----------

__global__ void k_detect(const int* __restrict__ ei, int* __restrict__ flag) {
  if (threadIdx.x == 0 && blockIdx.x == 0)
    *flag = (ei[1] == 0 && ei[3] == 0 && ei[5] == 0 && ei[7] == 0) ? 1 : 0;
}

__global__ __launch_bounds__(256) void k_zero(float4* __restrict__ p, int n4) {
  int i = blockIdx.x * 256 + threadIdx.x;
  if (i < n4) p[i] = make_float4(0.f, 0.f, 0.f, 0.f);
}

// dst histogram
__global__ __launch_bounds__(256) void k_hist(
    const void* __restrict__ ei, const int* __restrict__ flag64,
    int* __restrict__ hist, int E) {
  int e = blockIdx.x * 256 + threadIdx.x;
  if (e >= E) return;
  int d = (*flag64) ? (int)((const long long*)ei)[(size_t)E + e]
                    : ((const int*)ei)[(size_t)E + e];
  atomicAdd(&hist[d], 1);
}

// exclusive prefix sum over hist[N] -> cursor[N] (single block, 256 threads)
__global__ __launch_bounds__(256) void k_scan(
    const int* __restrict__ hist, int* __restrict__ cursor, int N) {
  __shared__ int part[256];
  int tid = threadIdx.x;
  int chunk = (N + 255) / 256;
  int s = 0;
  for (int i = 0; i < chunk; i++) {
    int idx = tid * chunk + i;
    if (idx < N) s += hist[idx];
  }
  part[tid] = s;
  __syncthreads();
  for (int off = 1; off < 256; off <<= 1) {
    int v = (tid >= off) ? part[tid - off] : 0;
    __syncthreads();
    part[tid] += v;
    __syncthreads();
  }
  int excl = (tid == 0) ? 0 : part[tid - 1];
  for (int i = 0; i < chunk; i++) {
    int idx = tid * chunk + i;
    if (idx < N) {
      cursor[idx] = excl;
      excl += hist[idx];
    }
  }
}

// scatter edges into dst-sorted order (src, dst, edge_attr)
__global__ __launch_bounds__(256) void k_scatter(
    const void* __restrict__ ei, const int* __restrict__ flag64,
    const float* __restrict__ ea, int* __restrict__ cursor,
    int* __restrict__ srcS, int* __restrict__ dstS, float* __restrict__ eaS, int E) {
  int e = blockIdx.x * 256 + threadIdx.x;
  if (e >= E) return;
  int is64 = *flag64;
  int s = is64 ? (int)((const long long*)ei)[e] : ((const int*)ei)[e];
  int d = is64 ? (int)((const long long*)ei)[(size_t)E + e]
               : ((const int*)ei)[(size_t)E + e];
  int p = atomicAdd(&cursor[d], 1);
  srcS[p] = s;
  dstS[p] = d;
  ((float4*)eaS)[p] = ((const float4*)ea)[e];
}

__global__ __launch_bounds__(256) void k_node_proj(
    const float* __restrict__ x, const int* __restrict__ a,
    const float* __restrict__ w, const float* __restrict__ b,
    float* __restrict__ h, int N) {
  int node = blockIdx.x;
  int j = threadIdx.x;
  float acc = b[j];
  acc = fmaf(x[node * 3 + 0], w[0 * H + j], acc);
  acc = fmaf(x[node * 3 + 1], w[1 * H + j], acc);
  acc = fmaf(x[node * 3 + 2], w[2 * H + j], acc);
  acc = fmaf((float)a[node], w[3 * H + j], acc);
  h[(size_t)node * H + j] = fmaxf(acc, 0.f);
}

// WtC[l][j][k] = (em_w2 @ lin_w[l])[k][j], hi/lo bf16 planes
__global__ __launch_bounds__(256, 2) void k_wcomb(
    const float* __restrict__ w2, const float* __restrict__ lin_w,
    unsigned short* __restrict__ wcTh, unsigned short* __restrict__ wcTl) {
  __shared__ __align__(16) float sA[32 * H];
  int l = blockIdx.x >> 3, tile = blockIdx.x & 7;
  int tid = threadIdx.x;
  const float4* src = (const float4*)(w2 + (size_t)tile * 32 * H);
#pragma unroll
  for (int it = 0; it < 8; it++) {
    int vi = it * 256 + tid;
    *(float4*)&sA[vi * 4] = src[vi];
  }
  __syncthreads();
  int lane_j = tid & 63, rg = tid >> 6;
  float acc[8][4];
  gemm_tile(sA, lin_w + (size_t)l * H * H, lane_j, rg, acc);
  unsigned short* oh = wcTh + (size_t)l * H * H;
  unsigned short* ol = wcTl + (size_t)l * H * H;
#pragma unroll
  for (int cc = 0; cc < 4; cc++) {
    int j = lane_j + 64 * cc;
#pragma unroll
    for (int mm = 0; mm < 8; mm++) {
      int k = tile * 32 + rg * 8 + mm;
      unsigned short hi, lo;
      fsplit(acc[mm][cc], hi, lo);
      oh[(size_t)j * H + k] = hi;
      ol[(size_t)j * H + k] = lo;
    }
  }
}

// beta[l] = em_b2 @ lin_w[l] + lin_b[l]
__global__ __launch_bounds__(256) void k_beta(
    const float* __restrict__ lin_w, const float* __restrict__ lin_b,
    const float* __restrict__ b2, float* __restrict__ beta) {
  int l = blockIdx.x, j = threadIdx.x;
  const float* W = lin_w + (size_t)l * H * H;
  float v = lin_b[l * H + j];
  for (int k = 0; k < H; k++) v = fmaf(b2[k], W[k * H + j], v);
  beta[l * H + j] = v;
}

// out_{h,l}[l][n][k] = bf16split(in[l][k][n])
__global__ __launch_bounds__(256) void k_transp(
    const float* __restrict__ in,
    unsigned short* __restrict__ outh, unsigned short* __restrict__ outl) {
  int l = blockIdx.z;
  int kb = blockIdx.x * 64, nb = blockIdx.y * 64;
  int tid = threadIdx.x;
  __shared__ float T[64][65];
  const float* src = in + (size_t)l * H * H;
#pragma unroll
  for (int it = 0; it < 16; it++) {
    int idx = it * 256 + tid;
    int kl = idx >> 6, nl = idx & 63;
    T[kl][nl] = src[(size_t)(kb + kl) * H + nb + nl];
  }
  __syncthreads();
  unsigned short* dh = outh + (size_t)l * H * H;
  unsigned short* dl = outl + (size_t)l * H * H;
#pragma unroll
  for (int it = 0; it < 8; it++) {
    int u = it * 256 + tid;
    int nl = u >> 5, k2 = (u & 31) * 2;
    unsigned short h0, l0, h1, l1;
    fsplit(T[k2][nl], h0, l0);
    fsplit(T[k2 + 1][nl], h1, l1);
    size_t o = (size_t)(nb + nl) * H + kb + k2;
    *(unsigned int*)&dh[o] = (unsigned int)h0 | ((unsigned int)h1 << 16);
    *(unsigned int*)&dl[o] = (unsigned int)l0 | ((unsigned int)l1 << 16);
  }
}

// ---------- per-layer MFMA kernels ----------

// Edge (dst-sorted), tile = TE(64) edges x 256 cols, 8 waves.
// A (edge-MLP output t) kept in SINGLE bf16 plane: e_l = A_hi*(B_hi+B_lo).
// -> 128 MFMA/wave (was 192), half A LDS traffic, 33.8 KB A-tile.
// Epilogue runs in TWO 32-row passes whose elbuf half aliases the A-tile:
// total LDS ~35.3 KB -> 4 blocks/CU (32 waves/CU, was 16).
__global__ __launch_bounds__(512, 8) void k_edge_mfma(
    const float* __restrict__ eaS,
    const float* __restrict__ w1, const float* __restrict__ b1,
    const unsigned short* __restrict__ Wth, const unsigned short* __restrict__ Wtl,
    const float* __restrict__ beta,
    const float* __restrict__ h, float* __restrict__ agg,
    const int* __restrict__ srcS, const int* __restrict__ dstS) {
  __shared__ __align__(16) char smem[TE * PITCH * 2];  // 33792 B: A-tile / elbuf half
  unsigned short* sAh = (unsigned short*)smem;
  float* elbuf = (float*)smem;                         // 32 * ELP * 4 = 33280 B
  __shared__ __align__(16) float sEA[TE * 4];
  __shared__ int sSrc[TE];
  __shared__ int sDst[TE];
  int tid = threadIdx.x;
  int base = blockIdx.x * TE;
  if (tid < TE) {
    sSrc[tid] = srcS[base + tid];
  } else if (tid < 2 * TE) {
    sDst[tid - TE] = dstS[base + tid - TE];
  } else if (tid < 3 * TE) {
    int t = tid - 2 * TE;
    ((float4*)sEA)[t] = ((const float4*)(eaS + (size_t)base * 4))[t];
  }
  __syncthreads();
  {  // t = relu(eaS @ w1 + b1) -> bf16 hi plane only (col pair, 16 rows/thread)
    int j2 = (tid & 127) * 2;
    int r0 = (tid >> 7) * 16;
    float wv0[4], wv1[4];
#pragma unroll
    for (int q = 0; q < 4; q++) { wv0[q] = w1[q * H + j2]; wv1[q] = w1[q * H + j2 + 1]; }
    float bb0 = b1[j2], bb1 = b1[j2 + 1];
#pragma unroll
    for (int m = r0; m < r0 + 16; m++) {
      float t0 = bb0, t1 = bb1;
#pragma unroll
      for (int q = 0; q < 4; q++) {
        float eav = sEA[m * 4 + q];
        t0 = fmaf(eav, wv0[q], t0);
        t1 = fmaf(eav, wv1[q], t1);
      }
      t0 = fmaxf(t0, 0.f); t1 = fmaxf(t1, 0.f);
      *(unsigned int*)&sAh[m * PITCH + j2] =
          (unsigned int)f2bf(t0) | ((unsigned int)f2bf(t1) << 16);
    }
  }
  __syncthreads();
  int lane = tid & 63, wv = tid >> 6;           // wv in 0..7
  int lane15 = lane & 15, quad = lane >> 4;
  int cg0 = wv * 2;                             // wave's 2 col-groups (32 cols)
  f32x4 acc[4][2];
#pragma unroll
  for (int i = 0; i < 4; i++)
#pragma unroll
    for (int c = 0; c < 2; c++) acc[i][c] = (f32x4){0.f, 0.f, 0.f, 0.f};
  const unsigned short* aph = sAh + lane15 * PITCH + quad * 8;
  const unsigned short* bph = Wth + (size_t)(cg0 * 16 + lane15) * H + quad * 8;
  const unsigned short* bpl = Wtl + (size_t)(cg0 * 16 + lane15) * H + quad * 8;
#pragma unroll
  for (int st = 0; st < 8; st++) {
    bf16x8 ah[4];
#pragma unroll
    for (int rg = 0; rg < 4; rg++)
      ah[rg] = *(const bf16x8*)(aph + rg * 16 * PITCH + st * 32);
#pragma unroll
    for (int cg = 0; cg < 2; cg++) {
      bf16x8 bhf = *(const bf16x8*)(bph + (size_t)cg * 16 * H + st * 32);
      bf16x8 blf = *(const bf16x8*)(bpl + (size_t)cg * 16 * H + st * 32);
#pragma unroll
      for (int rg = 0; rg < 4; rg++) {
        acc[rg][cg] = __builtin_amdgcn_mfma_f32_16x16x32_bf16(ah[rg], bhf, acc[rg][cg], 0, 0, 0);
        acc[rg][cg] = __builtin_amdgcn_mfma_f32_16x16x32_bf16(ah[rg], blf, acc[rg][cg], 0, 0, 0);
      }
    }
  }
  float bv[2];
#pragma unroll
  for (int cg = 0; cg < 2; cg++) bv[cg] = beta[(cg0 + cg) * 16 + lane15];
  __syncthreads();  // all waves done reading sAh; smem becomes elbuf half
  int jcol = tid & 255, half = tid >> 8;
#pragma unroll
  for (int pass = 0; pass < 2; pass++) {
    int rbase = pass * 32 + half * 16;
    // gather h for this pass's 16 rows (issued early; drains under elbuf phase)
    float hv[16];
#pragma unroll
    for (int m = 0; m < 16; m++) hv[m] = h[(size_t)sSrc[rbase + m] * H + jcol];
    // write elbuf rows pass*32..pass*32+31 from acc[pass*2 + rgi]
#pragma unroll
    for (int rgi = 0; rgi < 2; rgi++) {
      int rg = pass * 2 + rgi;
#pragma unroll
      for (int r = 0; r < 4; r++) {
        int row = rgi * 16 + quad * 4 + r;     // row within elbuf half (0..31)
#pragma unroll
        for (int cg = 0; cg < 2; cg++) {
          int j = (cg0 + cg) * 16 + lane15;
          elbuf[row * ELP + j] = acc[rg][cg][r] + bv[cg];
        }
      }
    }
    __syncthreads();  // elbuf half ready
    // segment-reduced scatter: thread (half,jcol) walks its 16 dst-sorted rows
    {
      const int* mdst = sDst + rbase;
      float run = 0.f;
      int prev = mdst[0];
#pragma unroll
      for (int m = 0; m < 16; m++) {
        int d = mdst[m];
        float msg = fmaxf(hv[m] + elbuf[(half * 16 + m) * ELP + jcol], 0.f);
        if (d != prev) {
          atomicAdd(&agg[(size_t)prev * H + jcol], run);
          run = 0.f;
          prev = d;
        }
        run += msg;
      }
      atomicAdd(&agg[(size_t)prev * H + jcol], run);
    }
    if (pass == 0) __syncthreads();  // pass-0 reads done before pass-1 overwrites
  }
}

// Node: z=h+agg; z1=relu(z@w1+b1); z2=z1@w2+b2; LN; h += relu(LN).
__global__ __launch_bounds__(256) void k_node_mfma(
    float* __restrict__ h, const float* __restrict__ agg,
    const unsigned short* __restrict__ w1Th, const unsigned short* __restrict__ w1Tl,
    const float* __restrict__ b1,
    const unsigned short* __restrict__ w2Th, const unsigned short* __restrict__ w2Tl,
    const float* __restrict__ b2,
    const float* __restrict__ lng, const float* __restrict__ lnb) {
  __shared__ __align__(16) unsigned short sAh[64 * PITCH];
  __shared__ __align__(16) unsigned short sAl[64 * PITCH];
  int tid = threadIdx.x;
  int base = blockIdx.x * 64;
  const float4* h4 = (const float4*)(h + (size_t)base * H);
  const float4* a4 = (const float4*)(agg + (size_t)base * H);
#pragma unroll
  for (int it = 0; it < 16; it++) {  // all 64 rows (4096 float4)
    int vi = it * 256 + tid;
    int row = vi >> 6, c4 = (vi & 63) * 4;
    float4 hv = h4[vi], av = a4[vi];
    float z[4] = {hv.x + av.x, hv.y + av.y, hv.z + av.z, hv.w + av.w};
    unsigned short hh[4], ll[4];
#pragma unroll
    for (int q = 0; q < 4; q++) fsplit(z[q], hh[q], ll[q]);
    uint2 uh, ul;
    uh.x = (unsigned int)hh[0] | ((unsigned int)hh[1] << 16);
    uh.y = (unsigned int)hh[2] | ((unsigned int)hh[3] << 16);
    ul.x = (unsigned int)ll[0] | ((unsigned int)ll[1] << 16);
    ul.y = (unsigned int)ll[2] | ((unsigned int)ll[3] << 16);
    *(uint2*)&sAh[row * PITCH + c4] = uh;
    *(uint2*)&sAl[row * PITCH + c4] = ul;
  }
  __syncthreads();
  int lane = tid & 63, wv = tid >> 6;
  int lane15 = lane & 15, quad = lane >> 4;
  const unsigned short* aph = sAh + (wv * 16 + lane15) * PITCH + quad * 8;
  const unsigned short* apl = sAl + (wv * 16 + lane15) * PITCH + quad * 8;
  f32x4 acc[16];
#pragma unroll
  for (int c = 0; c < 16; c++) acc[c] = (f32x4){0.f, 0.f, 0.f, 0.f};
  {
    const unsigned short* bph = w1Th + (size_t)lane15 * H + quad * 8;
    const unsigned short* bpl = w1Tl + (size_t)lane15 * H + quad * 8;
#pragma unroll
    for (int st = 0; st < 8; st++) {
      bf16x8 ahf = *(const bf16x8*)(aph + st * 32);
      bf16x8 alf = *(const bf16x8*)(apl + st * 32);
#pragma unroll
      for (int cg = 0; cg < 16; cg++) {
        bf16x8 bhf = *(const bf16x8*)(bph + (size_t)cg * 16 * H + st * 32);
        bf16x8 blf = *(const bf16x8*)(bpl + (size_t)cg * 16 * H + st * 32);
        acc[cg] = __builtin_amdgcn_mfma_f32_16x16x32_bf16(ahf, bhf, acc[cg], 0, 0, 0);
        acc[cg] = __builtin_amdgcn_mfma_f32_16x16x32_bf16(alf, bhf, acc[cg], 0, 0, 0);
        acc[cg] = __builtin_amdgcn_mfma_f32_16x16x32_bf16(ahf, blf, acc[cg], 0, 0, 0);
      }
    }
  }
  __syncthreads();
#pragma unroll
  for (int cg = 0; cg < 16; cg++) {
    float bb = b1[cg * 16 + lane15];
#pragma unroll
    for (int r = 0; r < 4; r++) {
      int row = wv * 16 + quad * 4 + r;
      float z1 = fmaxf(acc[cg][r] + bb, 0.f);
      unsigned short hh, ll;
      fsplit(z1, hh, ll);
      sAh[row * PITCH + cg * 16 + lane15] = hh;
      sAl[row * PITCH + cg * 16 + lane15] = ll;
    }
  }
  __syncthreads();
  f32x4 acc2[16];
#pragma unroll
  for (int c = 0; c < 16; c++) acc2[c] = (f32x4){0.f, 0.f, 0.f, 0.f};
  {
    const unsigned short* bph = w2Th + (size_t)lane15 * H + quad * 8;
    const unsigned short* bpl = w2Tl + (size_t)lane15 * H + quad * 8;
#pragma unroll
    for (int st = 0; st < 8; st++) {
      bf16x8 ahf = *(const bf16x8*)(aph + st * 32);
      bf16x8 alf = *(const bf16x8*)(apl + st * 32);
#pragma unroll
      for (int cg = 0; cg < 16; cg++) {
        bf16x8 bhf = *(const bf16x8*)(bph + (size_t)cg * 16 * H + st * 32);
        bf16x8 blf = *(const bf16x8*)(bpl + (size_t)cg * 16 * H + st * 32);
        acc2[cg] = __builtin_amdgcn_mfma_f32_16x16x32_bf16(ahf, bhf, acc2[cg], 0, 0, 0);
        acc2[cg] = __builtin_amdgcn_mfma_f32_16x16x32_bf16(alf, bhf, acc2[cg], 0, 0, 0);
        acc2[cg] = __builtin_amdgcn_mfma_f32_16x16x32_bf16(ahf, blf, acc2[cg], 0, 0, 0);
      }
    }
  }
  float b2v[16], gv[16], bbv[16];
#pragma unroll
  for (int cg = 0; cg < 16; cg++) {
    int j = cg * 16 + lane15;
    b2v[cg] = b2[j]; gv[cg] = lng[j]; bbv[cg] = lnb[j];
  }
#pragma unroll
  for (int r = 0; r < 4; r++) {
    float z2[16];
    float s = 0.f, ss = 0.f;
#pragma unroll
    for (int cg = 0; cg < 16; cg++) {
      z2[cg] = acc2[cg][r] + b2v[cg];
      s += z2[cg];
      ss = fmaf(z2[cg], z2[cg], ss);
    }
    s += __shfl_xor(s, 1, 64); ss += __shfl_xor(ss, 1, 64);
    s += __shfl_xor(s, 2, 64); ss += __shfl_xor(ss, 2, 64);
    s += __shfl_xor(s, 4, 64); ss += __shfl_xor(ss, 4, 64);
    s += __shfl_xor(s, 8, 64); ss += __shfl_xor(ss, 8, 64);
    float mu = s * (1.f / H);
    float var = ss * (1.f / H) - mu * mu;
    float rstd = rsqrtf(var + LN_EPS);
    int row = base + wv * 16 + quad * 4 + r;
    float* hr = h + (size_t)row * H;
#pragma unroll
    for (int cg = 0; cg < 16; cg++) {
      int j = cg * 16 + lane15;
      float v = fmaf((z2[cg] - mu) * rstd, gv[cg], bbv[cg]);
      hr[j] = hr[j] + fmaxf(v, 0.f);
    }
  }
}

// Partial mean-pool: block sums 64 rows into g[b][.] via atomics (fully parallel).
__global__ __launch_bounds__(256) void k_pool(
    const float* __restrict__ h, float* __restrict__ g, int n) {
  int tid = threadIdx.x;
  int row0 = blockIdx.x * 64;
  int b = row0 / n;                       // 64 | n, block never straddles graphs
  const float* hb = h + (size_t)row0 * H;
  float s0 = 0.f, s1 = 0.f, s2 = 0.f, s3 = 0.f;
  for (int i = 0; i < 64; i += 4) {
    s0 += hb[(size_t)(i + 0) * H + tid];
    s1 += hb[(size_t)(i + 1) * H + tid];
    s2 += hb[(size_t)(i + 2) * H + tid];
    s3 += hb[(size_t)(i + 3) * H + tid];
  }
  atomicAdd(&g[(size_t)b * H + tid], s0 + s1 + s2 + s3);
}

// Head MLP from pooled g. One block per graph.
__global__ __launch_bounds__(256) void k_head(
    const float* __restrict__ g,
    const float* __restrict__ w1, const float* __restrict__ b1,
    const float* __restrict__ w2, const float* __restrict__ b2,
    float* __restrict__ out, int n) {
  __shared__ float sG[H];
  __shared__ float sT[H];
  __shared__ float sR[4];
  int b = blockIdx.x, tid = threadIdx.x;
  sG[tid] = g[(size_t)b * H + tid] / (float)n;
  __syncthreads();
  float t = b1[tid];
  for (int k = 0; k < H; k++) t = fmaf(sG[k], w1[k * H + tid], t);
  sT[tid] = fmaxf(t, 0.f);
  __syncthreads();
  float p = sT[tid] * w2[tid];
#pragma unroll
  for (int off = 32; off > 0; off >>= 1) p += __shfl_xor(p, off, 64);
  if ((tid & 63) == 0) sR[tid >> 6] = p;
  __syncthreads();
  if (tid == 0) out[b] = sR[0] + sR[1] + sR[2] + sR[3] + b2[0];
}

// ---------- launcher ----------
extern "C" void kernel_launch(void* const* d_in, const int* in_sizes, int n_in,
                              void* d_out, int out_size, void* d_ws, size_t ws_size,
                              hipStream_t stream) {
  const float* x      = (const float*)d_in[0];
  const float* ea     = (const float*)d_in[1];
  const void*  ei     = d_in[2];
  const int*   a      = (const int*)d_in[3];
  const float* np_w   = (const float*)d_in[4];
  const float* np_b   = (const float*)d_in[5];
  const float* em_w1  = (const float*)d_in[6];
  const float* em_b1  = (const float*)d_in[7];
  const float* em_w2  = (const float*)d_in[8];
  const float* em_b2  = (const float*)d_in[9];
  const float* lin_w  = (const float*)d_in[10];
  const float* lin_b  = (const float*)d_in[11];
  const float* m_w1   = (const float*)d_in[12];
  const float* m_b1   = (const float*)d_in[13];
  const float* m_w2   = (const float*)d_in[14];
  const float* m_b2   = (const float*)d_in[15];
  const float* ln_g   = (const float*)d_in[16];
  const float* ln_b   = (const float*)d_in[17];
  const float* hd_w1  = (const float*)d_in[18];
  const float* hd_b1  = (const float*)d_in[19];
  const float* hd_w2  = (const float*)d_in[20];
  const float* hd_b2  = (const float*)d_in[21];

  int N = in_sizes[0] / 3;
  int E = in_sizes[1] / 4;
  int B = out_size;
  int n = N / B;

  // workspace layout (~82 MB)
  char* ws = (char*)d_ws;
  size_t off = 0;
  auto alloc = [&](size_t bytes) {
    char* p = ws + off;
    off += (bytes + 255) & ~(size_t)255;
    return p;
  };
  float* h    = (float*)alloc((size_t)N * H * 4);
  float* agg  = (float*)alloc((size_t)N * H * 4);
  unsigned short* wcTh = (unsigned short*)alloc((size_t)3 * H * H * 2);
  unsigned short* wcTl = (unsigned short*)alloc((size_t)3 * H * H * 2);
  unsigned short* w1Th = (unsigned short*)alloc((size_t)3 * H * H * 2);
  unsigned short* w1Tl = (unsigned short*)alloc((size_t)3 * H * H * 2);
  unsigned short* w2Th = (unsigned short*)alloc((size_t)3 * H * H * 2);
  unsigned short* w2Tl = (unsigned short*)alloc((size_t)3 * H * H * 2);
  float* beta  = (float*)alloc(3 * H * 4);
  int*   flag  = (int*)alloc(4);
  int*   hist  = (int*)alloc((size_t)N * 4);
  int*   curs  = (int*)alloc((size_t)N * 4);
  int*   srcS  = (int*)alloc((size_t)E * 4);
  int*   dstS  = (int*)alloc((size_t)E * 4);
  float* eaS   = (float*)alloc((size_t)E * 4 * 4);
  float* g     = (float*)alloc((size_t)B * H * 4);

  float* out = (float*)d_out;
  int ebl = (E + 255) / 256;

  k_detect<<<1, 64, 0, stream>>>((const int*)ei, flag);
  k_zero<<<(N + 1023) / 1024, 256, 0, stream>>>((float4*)hist, N / 4);
  k_hist<<<ebl, 256, 0, stream>>>(ei, flag, hist, E);
  k_scan<<<1, 256, 0, stream>>>(hist, curs, N);
  k_scatter<<<ebl, 256, 0, stream>>>(ei, flag, ea, curs, srcS, dstS, eaS, E);
  k_node_proj<<<N, 256, 0, stream>>>(x, a, np_w, np_b, h, N);
  k_wcomb<<<24, 256, 0, stream>>>(em_w2, lin_w, wcTh, wcTl);
  k_beta<<<3, 256, 0, stream>>>(lin_w, lin_b, em_b2, beta);
  k_transp<<<dim3(4, 4, 3), 256, 0, stream>>>(m_w1, w1Th, w1Tl);
  k_transp<<<dim3(4, 4, 3), 256, 0, stream>>>(m_w2, w2Th, w2Tl);

  int n4 = N * H / 4;
  for (int l = 0; l < 3; l++) {
    k_zero<<<(n4 + 255) / 256, 256, 0, stream>>>((float4*)agg, n4);
    k_edge_mfma<<<E / TE, 512, 0, stream>>>(eaS, em_w1, em_b1,
                                            wcTh + (size_t)l * H * H,
                                            wcTl + (size_t)l * H * H,
                                            beta + (size_t)l * H,
                                            h, agg, srcS, dstS);
    k_node_mfma<<<N / 64, 256, 0, stream>>>(h, agg,
                                            w1Th + (size_t)l * H * H,
                                            w1Tl + (size_t)l * H * H,
                                            m_b1 + (size_t)l * H,
                                            w2Th + (size_t)l * H * H,
                                            w2Tl + (size_t)l * H * H,
                                            m_b2 + (size_t)l * H,
                                            ln_g + (size_t)l * H, ln_b + (size_t)l * H);
  }
  int g4 = B * H / 4;
  k_zero<<<(g4 + 255) / 256, 256, 0, stream>>>((float4*)g, g4);
  k_pool<<<N / 64, 256, 0, stream>>>(h, g, n);
  k_head<<<B, 256, 0, stream>>>(g, hd_w1, hd_b1, hd_w2, hd_b2, out, n);
}

// Round 3
// 1654.375 us; speedup vs baseline: 1.1744x; 1.1744x over previous
//
#include <hip/hip_runtime.h>
#include <hip/hip_bf16.h>

#define H 256
#define LN_EPS 1e-5f
#define PITCH 264   // bf16 elements per LDS A-row (256 + 8 pad), 528 B
#define ELP 260     // f32 elements per LDS el-row (256 + 4 pad)
#define TE 64       // edges per tile (edge kernel)

typedef __attribute__((ext_vector_type(8))) short bf16x8;   // 8 bf16 = 4 VGPRs
typedef __attribute__((ext_vector_type(4))) float f32x4;    // MFMA 16x16 accum

// ---------- helpers ----------
__device__ __forceinline__ float bf2f(unsigned short u) {
  union { unsigned int i; float f; } v; v.i = ((unsigned int)u) << 16; return v.f;
}
__device__ __forceinline__ unsigned short f2bf(float f) {
  union { float f; unsigned int i; } v; v.f = f;
  unsigned int x = v.i;
  return (unsigned short)((x + 0x7fffu + ((x >> 16) & 1u)) >> 16);  // RNE
}
__device__ __forceinline__ void fsplit(float v, unsigned short& hi, unsigned short& lo) {
  hi = f2bf(v);
  lo = f2bf(v - bf2f(hi));
}

// fp32 register-tiled GEMM core (precompute only)
__device__ __forceinline__ void gemm_tile(const float* __restrict__ sA,
                                          const float* __restrict__ W,
                                          int lane_j, int rg, float acc[8][4]) {
#pragma unroll
  for (int mm = 0; mm < 8; mm++)
#pragma unroll
    for (int cc = 0; cc < 4; cc++) acc[mm][cc] = 0.f;
  for (int k = 0; k < H; k += 4) {
    float tvf[8][4];
#pragma unroll
    for (int mm = 0; mm < 8; mm++)
      *(float4*)&tvf[mm][0] = *(const float4*)&sA[(rg * 8 + mm) * H + k];
#pragma unroll
    for (int kk = 0; kk < 4; kk++) {
      const float* wr = W + (k + kk) * H + lane_j;
      float w0 = wr[0], w1 = wr[64], w2 = wr[128], w3 = wr[192];
#pragma unroll
      for (int mm = 0; mm < 8; mm++) {
        float av = tvf[mm][kk];
        acc[mm][0] = fmaf(av, w0, acc[mm][0]);
        acc[mm][1] = fmaf(av, w1, acc[mm][1]);
        acc[mm][2] = fmaf(av, w2, acc[mm][2]);
        acc[mm][3] = fmaf(av, w3, acc[mm][3]);
      }
    }
  }
}

// ---------- precompute kernels ----------

__global__ void k_detect(const int* __restrict__ ei, int* __restrict__ flag) {
  if (threadIdx.x == 0 && blockIdx.x == 0)
    *flag = (ei[1] == 0 && ei[3] == 0 && ei[5] == 0 && ei[7] == 0) ? 1 : 0;
}

__global__ __launch_bounds__(256) void k_zero(float4* __restrict__ p, int n4) {
  int i = blockIdx.x * 256 + threadIdx.x;
  if (i < n4) p[i] = make_float4(0.f, 0.f, 0.f, 0.f);
}

// dst histogram
__global__ __launch_bounds__(256) void k_hist(
    const void* __restrict__ ei, const int* __restrict__ flag64,
    int* __restrict__ hist, int E) {
  int e = blockIdx.x * 256 + threadIdx.x;
  if (e >= E) return;
  int d = (*flag64) ? (int)((const long long*)ei)[(size_t)E + e]
                    : ((const int*)ei)[(size_t)E + e];
  atomicAdd(&hist[d], 1);
}

// exclusive prefix sum over hist[N] -> cursor[N] (single block, 256 threads)
__global__ __launch_bounds__(256) void k_scan(
    const int* __restrict__ hist, int* __restrict__ cursor, int N) {
  __shared__ int part[256];
  int tid = threadIdx.x;
  int chunk = (N + 255) / 256;
  int s = 0;
  for (int i = 0; i < chunk; i++) {
    int idx = tid * chunk + i;
    if (idx < N) s += hist[idx];
  }
  part[tid] = s;
  __syncthreads();
  for (int off = 1; off < 256; off <<= 1) {
    int v = (tid >= off) ? part[tid - off] : 0;
    __syncthreads();
    part[tid] += v;
    __syncthreads();
  }
  int excl = (tid == 0) ? 0 : part[tid - 1];
  for (int i = 0; i < chunk; i++) {
    int idx = tid * chunk + i;
    if (idx < N) {
      cursor[idx] = excl;
      excl += hist[idx];
    }
  }
}

// scatter edges into dst-sorted order (src, dst, edge_attr)
__global__ __launch_bounds__(256) void k_scatter(
    const void* __restrict__ ei, const int* __restrict__ flag64,
    const float* __restrict__ ea, int* __restrict__ cursor,
    int* __restrict__ srcS, int* __restrict__ dstS, float* __restrict__ eaS, int E) {
  int e = blockIdx.x * 256 + threadIdx.x;
  if (e >= E) return;
  int is64 = *flag64;
  int s = is64 ? (int)((const long long*)ei)[e] : ((const int*)ei)[e];
  int d = is64 ? (int)((const long long*)ei)[(size_t)E + e]
               : ((const int*)ei)[(size_t)E + e];
  int p = atomicAdd(&cursor[d], 1);
  srcS[p] = s;
  dstS[p] = d;
  ((float4*)eaS)[p] = ((const float4*)ea)[e];
}

__global__ __launch_bounds__(256) void k_node_proj(
    const float* __restrict__ x, const int* __restrict__ a,
    const float* __restrict__ w, const float* __restrict__ b,
    float* __restrict__ h, int N) {
  int node = blockIdx.x;
  int j = threadIdx.x;
  float acc = b[j];
  acc = fmaf(x[node * 3 + 0], w[0 * H + j], acc);
  acc = fmaf(x[node * 3 + 1], w[1 * H + j], acc);
  acc = fmaf(x[node * 3 + 2], w[2 * H + j], acc);
  acc = fmaf((float)a[node], w[3 * H + j], acc);
  h[(size_t)node * H + j] = fmaxf(acc, 0.f);
}

// WtC[l][j][k] = (em_w2 @ lin_w[l])[k][j], hi/lo bf16 planes
__global__ __launch_bounds__(256, 2) void k_wcomb(
    const float* __restrict__ w2, const float* __restrict__ lin_w,
    unsigned short* __restrict__ wcTh, unsigned short* __restrict__ wcTl) {
  __shared__ __align__(16) float sA[32 * H];
  int l = blockIdx.x >> 3, tile = blockIdx.x & 7;
  int tid = threadIdx.x;
  const float4* src = (const float4*)(w2 + (size_t)tile * 32 * H);
#pragma unroll
  for (int it = 0; it < 8; it++) {
    int vi = it * 256 + tid;
    *(float4*)&sA[vi * 4] = src[vi];
  }
  __syncthreads();
  int lane_j = tid & 63, rg = tid >> 6;
  float acc[8][4];
  gemm_tile(sA, lin_w + (size_t)l * H * H, lane_j, rg, acc);
  unsigned short* oh = wcTh + (size_t)l * H * H;
  unsigned short* ol = wcTl + (size_t)l * H * H;
#pragma unroll
  for (int cc = 0; cc < 4; cc++) {
    int j = lane_j + 64 * cc;
#pragma unroll
    for (int mm = 0; mm < 8; mm++) {
      int k = tile * 32 + rg * 8 + mm;
      unsigned short hi, lo;
      fsplit(acc[mm][cc], hi, lo);
      oh[(size_t)j * H + k] = hi;
      ol[(size_t)j * H + k] = lo;
    }
  }
}

// beta[l] = em_b2 @ lin_w[l] + lin_b[l]
__global__ __launch_bounds__(256) void k_beta(
    const float* __restrict__ lin_w, const float* __restrict__ lin_b,
    const float* __restrict__ b2, float* __restrict__ beta) {
  int l = blockIdx.x, j = threadIdx.x;
  const float* W = lin_w + (size_t)l * H * H;
  float v = lin_b[l * H + j];
  for (int k = 0; k < H; k++) v = fmaf(b2[k], W[k * H + j], v);
  beta[l * H + j] = v;
}

// out_{h,l}[l][n][k] = bf16split(in[l][k][n])
__global__ __launch_bounds__(256) void k_transp(
    const float* __restrict__ in,
    unsigned short* __restrict__ outh, unsigned short* __restrict__ outl) {
  int l = blockIdx.z;
  int kb = blockIdx.x * 64, nb = blockIdx.y * 64;
  int tid = threadIdx.x;
  __shared__ float T[64][65];
  const float* src = in + (size_t)l * H * H;
#pragma unroll
  for (int it = 0; it < 16; it++) {
    int idx = it * 256 + tid;
    int kl = idx >> 6, nl = idx & 63;
    T[kl][nl] = src[(size_t)(kb + kl) * H + nb + nl];
  }
  __syncthreads();
  unsigned short* dh = outh + (size_t)l * H * H;
  unsigned short* dl = outl + (size_t)l * H * H;
#pragma unroll
  for (int it = 0; it < 8; it++) {
    int u = it * 256 + tid;
    int nl = u >> 5, k2 = (u & 31) * 2;
    unsigned short h0, l0, h1, l1;
    fsplit(T[k2][nl], h0, l0);
    fsplit(T[k2 + 1][nl], h1, l1);
    size_t o = (size_t)(nb + nl) * H + kb + k2;
    *(unsigned int*)&dh[o] = (unsigned int)h0 | ((unsigned int)h1 << 16);
    *(unsigned int*)&dl[o] = (unsigned int)l0 | ((unsigned int)l1 << 16);
  }
}

// ---------- per-layer MFMA kernels ----------

// Edge (dst-sorted), tile = TE(64) edges x 256 cols, 8 waves.
// A (edge-MLP output t) in SINGLE bf16 plane: e_l = A_hi*(B_hi+B_lo).
// Two-pass elbuf epilogue aliasing the A-tile: LDS ~35.3 KB.
// NOTE: launch_bounds min-waves MUST stay 4 (128-reg cap). R2's value of 8
// forced a 64-reg cap -> mass spill -> 784 MB scratch writes, 2.2x slower.
__global__ __launch_bounds__(512, 4) void k_edge_mfma(
    const float* __restrict__ eaS,
    const float* __restrict__ w1, const float* __restrict__ b1,
    const unsigned short* __restrict__ Wth, const unsigned short* __restrict__ Wtl,
    const float* __restrict__ beta,
    const float* __restrict__ h, float* __restrict__ agg,
    const int* __restrict__ srcS, const int* __restrict__ dstS) {
  __shared__ __align__(16) char smem[TE * PITCH * 2];  // 33792 B: A-tile / elbuf half
  unsigned short* sAh = (unsigned short*)smem;
  float* elbuf = (float*)smem;                         // 32 * ELP * 4 = 33280 B
  __shared__ __align__(16) float sEA[TE * 4];
  __shared__ int sSrc[TE];
  __shared__ int sDst[TE];
  int tid = threadIdx.x;
  int base = blockIdx.x * TE;
  if (tid < TE) {
    sSrc[tid] = srcS[base + tid];
  } else if (tid < 2 * TE) {
    sDst[tid - TE] = dstS[base + tid - TE];
  } else if (tid < 3 * TE) {
    int t = tid - 2 * TE;
    ((float4*)sEA)[t] = ((const float4*)(eaS + (size_t)base * 4))[t];
  }
  __syncthreads();
  {  // t = relu(eaS @ w1 + b1) -> bf16 hi plane only (col pair, 16 rows/thread)
    int j2 = (tid & 127) * 2;
    int r0 = (tid >> 7) * 16;
    float wv0[4], wv1[4];
#pragma unroll
    for (int q = 0; q < 4; q++) { wv0[q] = w1[q * H + j2]; wv1[q] = w1[q * H + j2 + 1]; }
    float bb0 = b1[j2], bb1 = b1[j2 + 1];
#pragma unroll
    for (int m = r0; m < r0 + 16; m++) {
      float t0 = bb0, t1 = bb1;
#pragma unroll
      for (int q = 0; q < 4; q++) {
        float eav = sEA[m * 4 + q];
        t0 = fmaf(eav, wv0[q], t0);
        t1 = fmaf(eav, wv1[q], t1);
      }
      t0 = fmaxf(t0, 0.f); t1 = fmaxf(t1, 0.f);
      *(unsigned int*)&sAh[m * PITCH + j2] =
          (unsigned int)f2bf(t0) | ((unsigned int)f2bf(t1) << 16);
    }
  }
  __syncthreads();
  int lane = tid & 63, wv = tid >> 6;           // wv in 0..7
  int lane15 = lane & 15, quad = lane >> 4;
  int cg0 = wv * 2;                             // wave's 2 col-groups (32 cols)
  f32x4 acc[4][2];
#pragma unroll
  for (int i = 0; i < 4; i++)
#pragma unroll
    for (int c = 0; c < 2; c++) acc[i][c] = (f32x4){0.f, 0.f, 0.f, 0.f};
  const unsigned short* aph = sAh + lane15 * PITCH + quad * 8;
  const unsigned short* bph = Wth + (size_t)(cg0 * 16 + lane15) * H + quad * 8;
  const unsigned short* bpl = Wtl + (size_t)(cg0 * 16 + lane15) * H + quad * 8;
#pragma unroll
  for (int st = 0; st < 8; st++) {
    bf16x8 ah[4];
#pragma unroll
    for (int rg = 0; rg < 4; rg++)
      ah[rg] = *(const bf16x8*)(aph + rg * 16 * PITCH + st * 32);
#pragma unroll
    for (int cg = 0; cg < 2; cg++) {
      bf16x8 bhf = *(const bf16x8*)(bph + (size_t)cg * 16 * H + st * 32);
      bf16x8 blf = *(const bf16x8*)(bpl + (size_t)cg * 16 * H + st * 32);
#pragma unroll
      for (int rg = 0; rg < 4; rg++) {
        acc[rg][cg] = __builtin_amdgcn_mfma_f32_16x16x32_bf16(ah[rg], bhf, acc[rg][cg], 0, 0, 0);
        acc[rg][cg] = __builtin_amdgcn_mfma_f32_16x16x32_bf16(ah[rg], blf, acc[rg][cg], 0, 0, 0);
      }
    }
  }
  float bv[2];
#pragma unroll
  for (int cg = 0; cg < 2; cg++) bv[cg] = beta[(cg0 + cg) * 16 + lane15];
  __syncthreads();  // all waves done reading sAh; smem becomes elbuf half
  int jcol = tid & 255, half = tid >> 8;
#pragma unroll
  for (int pass = 0; pass < 2; pass++) {
    int rbase = pass * 32 + half * 16;
    // gather h for this pass's 16 rows (issued early; drains under elbuf phase)
    float hv[16];
#pragma unroll
    for (int m = 0; m < 16; m++) hv[m] = h[(size_t)sSrc[rbase + m] * H + jcol];
    // write elbuf rows pass*32..pass*32+31 from acc[pass*2 + rgi]
#pragma unroll
    for (int rgi = 0; rgi < 2; rgi++) {
      int rg = pass * 2 + rgi;
#pragma unroll
      for (int r = 0; r < 4; r++) {
        int row = rgi * 16 + quad * 4 + r;     // row within elbuf half (0..31)
#pragma unroll
        for (int cg = 0; cg < 2; cg++) {
          int j = (cg0 + cg) * 16 + lane15;
          elbuf[row * ELP + j] = acc[rg][cg][r] + bv[cg];
        }
      }
    }
    __syncthreads();  // elbuf half ready
    // segment-reduced scatter: thread (half,jcol) walks its 16 dst-sorted rows
    {
      const int* mdst = sDst + rbase;
      float run = 0.f;
      int prev = mdst[0];
#pragma unroll
      for (int m = 0; m < 16; m++) {
        int d = mdst[m];
        float msg = fmaxf(hv[m] + elbuf[(half * 16 + m) * ELP + jcol], 0.f);
        if (d != prev) {
          atomicAdd(&agg[(size_t)prev * H + jcol], run);
          run = 0.f;
          prev = d;
        }
        run += msg;
      }
      atomicAdd(&agg[(size_t)prev * H + jcol], run);
    }
    if (pass == 0) __syncthreads();  // pass-0 reads done before pass-1 overwrites
  }
}

// Node: z=h+agg; z1=relu(z@w1+b1); z2=z1@w2+b2; LN; h += relu(LN).
// A-side (z, z1) in SINGLE bf16 plane (validated on edge path); B split hi+lo.
// -> 2 MFMA per fragment (was 3), one LDS plane (33.8 KB) -> 4 blocks/CU.
__global__ __launch_bounds__(256) void k_node_mfma(
    float* __restrict__ h, const float* __restrict__ agg,
    const unsigned short* __restrict__ w1Th, const unsigned short* __restrict__ w1Tl,
    const float* __restrict__ b1,
    const unsigned short* __restrict__ w2Th, const unsigned short* __restrict__ w2Tl,
    const float* __restrict__ b2,
    const float* __restrict__ lng, const float* __restrict__ lnb) {
  __shared__ __align__(16) unsigned short sAh[64 * PITCH];
  int tid = threadIdx.x;
  int base = blockIdx.x * 64;
  const float4* h4 = (const float4*)(h + (size_t)base * H);
  const float4* a4 = (const float4*)(agg + (size_t)base * H);
#pragma unroll
  for (int it = 0; it < 16; it++) {  // all 64 rows (4096 float4)
    int vi = it * 256 + tid;
    int row = vi >> 6, c4 = (vi & 63) * 4;
    float4 hv = h4[vi], av = a4[vi];
    float z[4] = {hv.x + av.x, hv.y + av.y, hv.z + av.z, hv.w + av.w};
    uint2 uh;
    uh.x = (unsigned int)f2bf(z[0]) | ((unsigned int)f2bf(z[1]) << 16);
    uh.y = (unsigned int)f2bf(z[2]) | ((unsigned int)f2bf(z[3]) << 16);
    *(uint2*)&sAh[row * PITCH + c4] = uh;
  }
  __syncthreads();
  int lane = tid & 63, wv = tid >> 6;
  int lane15 = lane & 15, quad = lane >> 4;
  const unsigned short* aph = sAh + (wv * 16 + lane15) * PITCH + quad * 8;
  f32x4 acc[16];
#pragma unroll
  for (int c = 0; c < 16; c++) acc[c] = (f32x4){0.f, 0.f, 0.f, 0.f};
  {
    const unsigned short* bph = w1Th + (size_t)lane15 * H + quad * 8;
    const unsigned short* bpl = w1Tl + (size_t)lane15 * H + quad * 8;
#pragma unroll
    for (int st = 0; st < 8; st++) {
      bf16x8 ahf = *(const bf16x8*)(aph + st * 32);
#pragma unroll
      for (int cg = 0; cg < 16; cg++) {
        bf16x8 bhf = *(const bf16x8*)(bph + (size_t)cg * 16 * H + st * 32);
        bf16x8 blf = *(const bf16x8*)(bpl + (size_t)cg * 16 * H + st * 32);
        acc[cg] = __builtin_amdgcn_mfma_f32_16x16x32_bf16(ahf, bhf, acc[cg], 0, 0, 0);
        acc[cg] = __builtin_amdgcn_mfma_f32_16x16x32_bf16(ahf, blf, acc[cg], 0, 0, 0);
      }
    }
  }
  __syncthreads();
#pragma unroll
  for (int cg = 0; cg < 16; cg++) {
    float bb = b1[cg * 16 + lane15];
#pragma unroll
    for (int r = 0; r < 4; r++) {
      int row = wv * 16 + quad * 4 + r;
      float z1 = fmaxf(acc[cg][r] + bb, 0.f);
      sAh[row * PITCH + cg * 16 + lane15] = f2bf(z1);
    }
  }
  __syncthreads();
  f32x4 acc2[16];
#pragma unroll
  for (int c = 0; c < 16; c++) acc2[c] = (f32x4){0.f, 0.f, 0.f, 0.f};
  {
    const unsigned short* bph = w2Th + (size_t)lane15 * H + quad * 8;
    const unsigned short* bpl = w2Tl + (size_t)lane15 * H + quad * 8;
#pragma unroll
    for (int st = 0; st < 8; st++) {
      bf16x8 ahf = *(const bf16x8*)(aph + st * 32);
#pragma unroll
      for (int cg = 0; cg < 16; cg++) {
        bf16x8 bhf = *(const bf16x8*)(bph + (size_t)cg * 16 * H + st * 32);
        bf16x8 blf = *(const bf16x8*)(bpl + (size_t)cg * 16 * H + st * 32);
        acc2[cg] = __builtin_amdgcn_mfma_f32_16x16x32_bf16(ahf, bhf, acc2[cg], 0, 0, 0);
        acc2[cg] = __builtin_amdgcn_mfma_f32_16x16x32_bf16(ahf, blf, acc2[cg], 0, 0, 0);
      }
    }
  }
  float b2v[16], gv[16], bbv[16];
#pragma unroll
  for (int cg = 0; cg < 16; cg++) {
    int j = cg * 16 + lane15;
    b2v[cg] = b2[j]; gv[cg] = lng[j]; bbv[cg] = lnb[j];
  }
#pragma unroll
  for (int r = 0; r < 4; r++) {
    float z2[16];
    float s = 0.f, ss = 0.f;
#pragma unroll
    for (int cg = 0; cg < 16; cg++) {
      z2[cg] = acc2[cg][r] + b2v[cg];
      s += z2[cg];
      ss = fmaf(z2[cg], z2[cg], ss);
    }
    s += __shfl_xor(s, 1, 64); ss += __shfl_xor(ss, 1, 64);
    s += __shfl_xor(s, 2, 64); ss += __shfl_xor(ss, 2, 64);
    s += __shfl_xor(s, 4, 64); ss += __shfl_xor(ss, 4, 64);
    s += __shfl_xor(s, 8, 64); ss += __shfl_xor(ss, 8, 64);
    float mu = s * (1.f / H);
    float var = ss * (1.f / H) - mu * mu;
    float rstd = rsqrtf(var + LN_EPS);
    int row = base + wv * 16 + quad * 4 + r;
    float* hr = h + (size_t)row * H;
#pragma unroll
    for (int cg = 0; cg < 16; cg++) {
      int j = cg * 16 + lane15;
      float v = fmaf((z2[cg] - mu) * rstd, gv[cg], bbv[cg]);
      hr[j] = hr[j] + fmaxf(v, 0.f);
    }
  }
}

// Partial mean-pool: block sums 64 rows into g[b][.] via atomics (fully parallel).
__global__ __launch_bounds__(256) void k_pool(
    const float* __restrict__ h, float* __restrict__ g, int n) {
  int tid = threadIdx.x;
  int row0 = blockIdx.x * 64;
  int b = row0 / n;                       // 64 | n, block never straddles graphs
  const float* hb = h + (size_t)row0 * H;
  float s0 = 0.f, s1 = 0.f, s2 = 0.f, s3 = 0.f;
  for (int i = 0; i < 64; i += 4) {
    s0 += hb[(size_t)(i + 0) * H + tid];
    s1 += hb[(size_t)(i + 1) * H + tid];
    s2 += hb[(size_t)(i + 2) * H + tid];
    s3 += hb[(size_t)(i + 3) * H + tid];
  }
  atomicAdd(&g[(size_t)b * H + tid], s0 + s1 + s2 + s3);
}

// Head MLP from pooled g. One block per graph.
__global__ __launch_bounds__(256) void k_head(
    const float* __restrict__ g,
    const float* __restrict__ w1, const float* __restrict__ b1,
    const float* __restrict__ w2, const float* __restrict__ b2,
    float* __restrict__ out, int n) {
  __shared__ float sG[H];
  __shared__ float sT[H];
  __shared__ float sR[4];
  int b = blockIdx.x, tid = threadIdx.x;
  sG[tid] = g[(size_t)b * H + tid] / (float)n;
  __syncthreads();
  float t = b1[tid];
  for (int k = 0; k < H; k++) t = fmaf(sG[k], w1[k * H + tid], t);
  sT[tid] = fmaxf(t, 0.f);
  __syncthreads();
  float p = sT[tid] * w2[tid];
#pragma unroll
  for (int off = 32; off > 0; off >>= 1) p += __shfl_xor(p, off, 64);
  if ((tid & 63) == 0) sR[tid >> 6] = p;
  __syncthreads();
  if (tid == 0) out[b] = sR[0] + sR[1] + sR[2] + sR[3] + b2[0];
}

// ---------- launcher ----------
extern "C" void kernel_launch(void* const* d_in, const int* in_sizes, int n_in,
                              void* d_out, int out_size, void* d_ws, size_t ws_size,
                              hipStream_t stream) {
  const float* x      = (const float*)d_in[0];
  const float* ea     = (const float*)d_in[1];
  const void*  ei     = d_in[2];
  const int*   a      = (const int*)d_in[3];
  const float* np_w   = (const float*)d_in[4];
  const float* np_b   = (const float*)d_in[5];
  const float* em_w1  = (const float*)d_in[6];
  const float* em_b1  = (const float*)d_in[7];
  const float* em_w2  = (const float*)d_in[8];
  const float* em_b2  = (const float*)d_in[9];
  const float* lin_w  = (const float*)d_in[10];
  const float* lin_b  = (const float*)d_in[11];
  const float* m_w1   = (const float*)d_in[12];
  const float* m_b1   = (const float*)d_in[13];
  const float* m_w2   = (const float*)d_in[14];
  const float* m_b2   = (const float*)d_in[15];
  const float* ln_g   = (const float*)d_in[16];
  const float* ln_b   = (const float*)d_in[17];
  const float* hd_w1  = (const float*)d_in[18];
  const float* hd_b1  = (const float*)d_in[19];
  const float* hd_w2  = (const float*)d_in[20];
  const float* hd_b2  = (const float*)d_in[21];

  int N = in_sizes[0] / 3;
  int E = in_sizes[1] / 4;
  int B = out_size;
  int n = N / B;

  // workspace layout (~82 MB)
  char* ws = (char*)d_ws;
  size_t off = 0;
  auto alloc = [&](size_t bytes) {
    char* p = ws + off;
    off += (bytes + 255) & ~(size_t)255;
    return p;
  };
  float* h    = (float*)alloc((size_t)N * H * 4);
  float* agg  = (float*)alloc((size_t)N * H * 4);
  unsigned short* wcTh = (unsigned short*)alloc((size_t)3 * H * H * 2);
  unsigned short* wcTl = (unsigned short*)alloc((size_t)3 * H * H * 2);
  unsigned short* w1Th = (unsigned short*)alloc((size_t)3 * H * H * 2);
  unsigned short* w1Tl = (unsigned short*)alloc((size_t)3 * H * H * 2);
  unsigned short* w2Th = (unsigned short*)alloc((size_t)3 * H * H * 2);
  unsigned short* w2Tl = (unsigned short*)alloc((size_t)3 * H * H * 2);
  float* beta  = (float*)alloc(3 * H * 4);
  int*   flag  = (int*)alloc(4);
  int*   hist  = (int*)alloc((size_t)N * 4);
  int*   curs  = (int*)alloc((size_t)N * 4);
  int*   srcS  = (int*)alloc((size_t)E * 4);
  int*   dstS  = (int*)alloc((size_t)E * 4);
  float* eaS   = (float*)alloc((size_t)E * 4 * 4);
  float* g     = (float*)alloc((size_t)B * H * 4);

  float* out = (float*)d_out;
  int ebl = (E + 255) / 256;

  k_detect<<<1, 64, 0, stream>>>((const int*)ei, flag);
  k_zero<<<(N + 1023) / 1024, 256, 0, stream>>>((float4*)hist, N / 4);
  k_hist<<<ebl, 256, 0, stream>>>(ei, flag, hist, E);
  k_scan<<<1, 256, 0, stream>>>(hist, curs, N);
  k_scatter<<<ebl, 256, 0, stream>>>(ei, flag, ea, curs, srcS, dstS, eaS, E);
  k_node_proj<<<N, 256, 0, stream>>>(x, a, np_w, np_b, h, N);
  k_wcomb<<<24, 256, 0, stream>>>(em_w2, lin_w, wcTh, wcTl);
  k_beta<<<3, 256, 0, stream>>>(lin_w, lin_b, em_b2, beta);
  k_transp<<<dim3(4, 4, 3), 256, 0, stream>>>(m_w1, w1Th, w1Tl);
  k_transp<<<dim3(4, 4, 3), 256, 0, stream>>>(m_w2, w2Th, w2Tl);

  int n4 = N * H / 4;
  for (int l = 0; l < 3; l++) {
    k_zero<<<(n4 + 255) / 256, 256, 0, stream>>>((float4*)agg, n4);
    k_edge_mfma<<<E / TE, 512, 0, stream>>>(eaS, em_w1, em_b1,
                                            wcTh + (size_t)l * H * H,
                                            wcTl + (size_t)l * H * H,
                                            beta + (size_t)l * H,
                                            h, agg, srcS, dstS);
    k_node_mfma<<<N / 64, 256, 0, stream>>>(h, agg,
                                            w1Th + (size_t)l * H * H,
                                            w1Tl + (size_t)l * H * H,
                                            m_b1 + (size_t)l * H,
                                            w2Th + (size_t)l * H * H,
                                            w2Tl + (size_t)l * H * H,
                                            m_b2 + (size_t)l * H,
                                            ln_g + (size_t)l * H, ln_b + (size_t)l * H);
  }
  int g4 = B * H / 4;
  k_zero<<<(g4 + 255) / 256, 256, 0, stream>>>((float4*)g, g4);
  k_pool<<<N / 64, 256, 0, stream>>>(h, g, n);
  k_head<<<B, 256, 0, stream>>>(g, hd_w1, hd_b1, hd_w2, hd_b2, out, n);
}

// Round 4
// 1066.184 us; speedup vs baseline: 1.8223x; 1.5517x over previous
//
#include <hip/hip_runtime.h>
#include <hip/hip_bf16.h>

#define H 256
#define LN_EPS 1e-5f
#define PITCH 264   // bf16 elements per LDS A-row (256 + 8 pad), 528 B
#define ELP 260     // f32 elements per LDS el-row (256 + 4 pad)
#define TE 64       // edges per tile (edge kernel)

typedef __attribute__((ext_vector_type(8))) short bf16x8;   // 8 bf16 = 4 VGPRs
typedef __attribute__((ext_vector_type(4))) float f32x4;    // MFMA 16x16 accum

// ---------- helpers ----------
__device__ __forceinline__ float bf2f(unsigned short u) {
  union { unsigned int i; float f; } v; v.i = ((unsigned int)u) << 16; return v.f;
}
__device__ __forceinline__ unsigned short f2bf(float f) {
  union { float f; unsigned int i; } v; v.f = f;
  unsigned int x = v.i;
  return (unsigned short)((x + 0x7fffu + ((x >> 16) & 1u)) >> 16);  // RNE
}
__device__ __forceinline__ void fsplit(float v, unsigned short& hi, unsigned short& lo) {
  hi = f2bf(v);
  lo = f2bf(v - bf2f(hi));
}

// fp32 register-tiled GEMM core (precompute only)
__device__ __forceinline__ void gemm_tile(const float* __restrict__ sA,
                                          const float* __restrict__ W,
                                          int lane_j, int rg, float acc[8][4]) {
#pragma unroll
  for (int mm = 0; mm < 8; mm++)
#pragma unroll
    for (int cc = 0; cc < 4; cc++) acc[mm][cc] = 0.f;
  for (int k = 0; k < H; k += 4) {
    float tvf[8][4];
#pragma unroll
    for (int mm = 0; mm < 8; mm++)
      *(float4*)&tvf[mm][0] = *(const float4*)&sA[(rg * 8 + mm) * H + k];
#pragma unroll
    for (int kk = 0; kk < 4; kk++) {
      const float* wr = W + (k + kk) * H + lane_j;
      float w0 = wr[0], w1 = wr[64], w2 = wr[128], w3 = wr[192];
#pragma unroll
      for (int mm = 0; mm < 8; mm++) {
        float av = tvf[mm][kk];
        acc[mm][0] = fmaf(av, w0, acc[mm][0]);
        acc[mm][1] = fmaf(av, w1, acc[mm][1]);
        acc[mm][2] = fmaf(av, w2, acc[mm][2]);
        acc[mm][3] = fmaf(av, w3, acc[mm][3]);
      }
    }
  }
}

// ---------- precompute kernels ----------

__global__ void k_detect(const int* __restrict__ ei, int* __restrict__ flag) {
  if (threadIdx.x == 0 && blockIdx.x == 0)
    *flag = (ei[1] == 0 && ei[3] == 0 && ei[5] == 0 && ei[7] == 0) ? 1 : 0;
}

__global__ __launch_bounds__(256) void k_zero(float4* __restrict__ p, int n4) {
  int i = blockIdx.x * 256 + threadIdx.x;
  if (i < n4) p[i] = make_float4(0.f, 0.f, 0.f, 0.f);
}

// dst histogram
__global__ __launch_bounds__(256) void k_hist(
    const void* __restrict__ ei, const int* __restrict__ flag64,
    int* __restrict__ hist, int E) {
  int e = blockIdx.x * 256 + threadIdx.x;
  if (e >= E) return;
  int d = (*flag64) ? (int)((const long long*)ei)[(size_t)E + e]
                    : ((const int*)ei)[(size_t)E + e];
  atomicAdd(&hist[d], 1);
}

// exclusive prefix sum over hist[N] -> cursor[N] (single block, 256 threads)
__global__ __launch_bounds__(256) void k_scan(
    const int* __restrict__ hist, int* __restrict__ cursor, int N) {
  __shared__ int part[256];
  int tid = threadIdx.x;
  int chunk = (N + 255) / 256;
  int s = 0;
  for (int i = 0; i < chunk; i++) {
    int idx = tid * chunk + i;
    if (idx < N) s += hist[idx];
  }
  part[tid] = s;
  __syncthreads();
  for (int off = 1; off < 256; off <<= 1) {
    int v = (tid >= off) ? part[tid - off] : 0;
    __syncthreads();
    part[tid] += v;
    __syncthreads();
  }
  int excl = (tid == 0) ? 0 : part[tid - 1];
  for (int i = 0; i < chunk; i++) {
    int idx = tid * chunk + i;
    if (idx < N) {
      cursor[idx] = excl;
      excl += hist[idx];
    }
  }
}

// scatter edges into dst-sorted order (src, dst, edge_attr)
__global__ __launch_bounds__(256) void k_scatter(
    const void* __restrict__ ei, const int* __restrict__ flag64,
    const float* __restrict__ ea, int* __restrict__ cursor,
    int* __restrict__ srcS, int* __restrict__ dstS, float* __restrict__ eaS, int E) {
  int e = blockIdx.x * 256 + threadIdx.x;
  if (e >= E) return;
  int is64 = *flag64;
  int s = is64 ? (int)((const long long*)ei)[e] : ((const int*)ei)[e];
  int d = is64 ? (int)((const long long*)ei)[(size_t)E + e]
               : ((const int*)ei)[(size_t)E + e];
  int p = atomicAdd(&cursor[d], 1);
  srcS[p] = s;
  dstS[p] = d;
  ((float4*)eaS)[p] = ((const float4*)ea)[e];
}

__global__ __launch_bounds__(256) void k_node_proj(
    const float* __restrict__ x, const int* __restrict__ a,
    const float* __restrict__ w, const float* __restrict__ b,
    float* __restrict__ h, int N) {
  int node = blockIdx.x;
  int j = threadIdx.x;
  float acc = b[j];
  acc = fmaf(x[node * 3 + 0], w[0 * H + j], acc);
  acc = fmaf(x[node * 3 + 1], w[1 * H + j], acc);
  acc = fmaf(x[node * 3 + 2], w[2 * H + j], acc);
  acc = fmaf((float)a[node], w[3 * H + j], acc);
  h[(size_t)node * H + j] = fmaxf(acc, 0.f);
}

// WtC[l][j][k] = (em_w2 @ lin_w[l])[k][j], hi/lo bf16 planes
__global__ __launch_bounds__(256, 2) void k_wcomb(
    const float* __restrict__ w2, const float* __restrict__ lin_w,
    unsigned short* __restrict__ wcTh, unsigned short* __restrict__ wcTl) {
  __shared__ __align__(16) float sA[32 * H];
  int l = blockIdx.x >> 3, tile = blockIdx.x & 7;
  int tid = threadIdx.x;
  const float4* src = (const float4*)(w2 + (size_t)tile * 32 * H);
#pragma unroll
  for (int it = 0; it < 8; it++) {
    int vi = it * 256 + tid;
    *(float4*)&sA[vi * 4] = src[vi];
  }
  __syncthreads();
  int lane_j = tid & 63, rg = tid >> 6;
  float acc[8][4];
  gemm_tile(sA, lin_w + (size_t)l * H * H, lane_j, rg, acc);
  unsigned short* oh = wcTh + (size_t)l * H * H;
  unsigned short* ol = wcTl + (size_t)l * H * H;
#pragma unroll
  for (int cc = 0; cc < 4; cc++) {
    int j = lane_j + 64 * cc;
#pragma unroll
    for (int mm = 0; mm < 8; mm++) {
      int k = tile * 32 + rg * 8 + mm;
      unsigned short hi, lo;
      fsplit(acc[mm][cc], hi, lo);
      oh[(size_t)j * H + k] = hi;
      ol[(size_t)j * H + k] = lo;
    }
  }
}

// beta[l] = em_b2 @ lin_w[l] + lin_b[l]
__global__ __launch_bounds__(256) void k_beta(
    const float* __restrict__ lin_w, const float* __restrict__ lin_b,
    const float* __restrict__ b2, float* __restrict__ beta) {
  int l = blockIdx.x, j = threadIdx.x;
  const float* W = lin_w + (size_t)l * H * H;
  float v = lin_b[l * H + j];
  for (int k = 0; k < H; k++) v = fmaf(b2[k], W[k * H + j], v);
  beta[l * H + j] = v;
}

// out_{h,l}[l][n][k] = bf16split(in[l][k][n])
__global__ __launch_bounds__(256) void k_transp(
    const float* __restrict__ in,
    unsigned short* __restrict__ outh, unsigned short* __restrict__ outl) {
  int l = blockIdx.z;
  int kb = blockIdx.x * 64, nb = blockIdx.y * 64;
  int tid = threadIdx.x;
  __shared__ float T[64][65];
  const float* src = in + (size_t)l * H * H;
#pragma unroll
  for (int it = 0; it < 16; it++) {
    int idx = it * 256 + tid;
    int kl = idx >> 6, nl = idx & 63;
    T[kl][nl] = src[(size_t)(kb + kl) * H + nb + nl];
  }
  __syncthreads();
  unsigned short* dh = outh + (size_t)l * H * H;
  unsigned short* dl = outl + (size_t)l * H * H;
#pragma unroll
  for (int it = 0; it < 8; it++) {
    int u = it * 256 + tid;
    int nl = u >> 5, k2 = (u & 31) * 2;
    unsigned short h0, l0, h1, l1;
    fsplit(T[k2][nl], h0, l0);
    fsplit(T[k2 + 1][nl], h1, l1);
    size_t o = (size_t)(nb + nl) * H + kb + k2;
    *(unsigned int*)&dh[o] = (unsigned int)h0 | ((unsigned int)h1 << 16);
    *(unsigned int*)&dl[o] = (unsigned int)l0 | ((unsigned int)l1 << 16);
  }
}

// ---------- per-layer MFMA kernels ----------

// Edge (dst-sorted), tile = TE(64) edges x 256 cols, 8 waves.
// A hi-plane only AND B hi-plane only: e_l = A_hi * B_hi (64 MFMA/wave,
// 16 B-loads/wave -> halves the L2 B stream, the dominant global traffic).
// Single-pass 64-row elbuf aliased over the A-tile (one fewer barrier).
// launch_bounds min-waves MUST stay 4 (128-reg cap; 8 caused R2 spill storm).
__global__ __launch_bounds__(512, 4) void k_edge_mfma(
    const float* __restrict__ eaS,
    const float* __restrict__ w1, const float* __restrict__ b1,
    const unsigned short* __restrict__ Wth, const unsigned short* __restrict__ Wtl,
    const float* __restrict__ beta,
    const float* __restrict__ h, float* __restrict__ agg,
    const int* __restrict__ srcS, const int* __restrict__ dstS) {
  __shared__ __align__(16) char smem[TE * ELP * 4];  // 66560 B: elbuf; A-tile aliased
  unsigned short* sAh = (unsigned short*)smem;       // 64*PITCH*2 = 33792 B
  float* elbuf = (float*)smem;
  __shared__ __align__(16) float sEA[TE * 4];
  __shared__ int sSrc[TE];
  __shared__ int sDst[TE];
  int tid = threadIdx.x;
  int base = blockIdx.x * TE;
  if (tid < TE) {
    sSrc[tid] = srcS[base + tid];
  } else if (tid < 2 * TE) {
    sDst[tid - TE] = dstS[base + tid - TE];
  } else if (tid < 3 * TE) {
    int t = tid - 2 * TE;
    ((float4*)sEA)[t] = ((const float4*)(eaS + (size_t)base * 4))[t];
  }
  __syncthreads();
  {  // t = relu(eaS @ w1 + b1) -> bf16 hi plane only (col pair, 16 rows/thread)
    int j2 = (tid & 127) * 2;
    int r0 = (tid >> 7) * 16;
    float wv0[4], wv1[4];
#pragma unroll
    for (int q = 0; q < 4; q++) { wv0[q] = w1[q * H + j2]; wv1[q] = w1[q * H + j2 + 1]; }
    float bb0 = b1[j2], bb1 = b1[j2 + 1];
#pragma unroll
    for (int m = r0; m < r0 + 16; m++) {
      float t0 = bb0, t1 = bb1;
#pragma unroll
      for (int q = 0; q < 4; q++) {
        float eav = sEA[m * 4 + q];
        t0 = fmaf(eav, wv0[q], t0);
        t1 = fmaf(eav, wv1[q], t1);
      }
      t0 = fmaxf(t0, 0.f); t1 = fmaxf(t1, 0.f);
      *(unsigned int*)&sAh[m * PITCH + j2] =
          (unsigned int)f2bf(t0) | ((unsigned int)f2bf(t1) << 16);
    }
  }
  __syncthreads();
  int lane = tid & 63, wv = tid >> 6;           // wv in 0..7
  int lane15 = lane & 15, quad = lane >> 4;
  int cg0 = wv * 2;                             // wave's 2 col-groups (32 cols)
  f32x4 acc[4][2];
#pragma unroll
  for (int i = 0; i < 4; i++)
#pragma unroll
    for (int c = 0; c < 2; c++) acc[i][c] = (f32x4){0.f, 0.f, 0.f, 0.f};
  const unsigned short* aph = sAh + lane15 * PITCH + quad * 8;
  const unsigned short* bph = Wth + (size_t)(cg0 * 16 + lane15) * H + quad * 8;
#pragma unroll
  for (int st = 0; st < 8; st++) {
    bf16x8 ah[4];
#pragma unroll
    for (int rg = 0; rg < 4; rg++)
      ah[rg] = *(const bf16x8*)(aph + rg * 16 * PITCH + st * 32);
#pragma unroll
    for (int cg = 0; cg < 2; cg++) {
      bf16x8 bhf = *(const bf16x8*)(bph + (size_t)cg * 16 * H + st * 32);
#pragma unroll
      for (int rg = 0; rg < 4; rg++)
        acc[rg][cg] = __builtin_amdgcn_mfma_f32_16x16x32_bf16(ah[rg], bhf, acc[rg][cg], 0, 0, 0);
    }
  }
  float bv[2];
#pragma unroll
  for (int cg = 0; cg < 2; cg++) bv[cg] = beta[(cg0 + cg) * 16 + lane15];
  // h-gather: issue before the A-done barrier; loads stay in flight across it.
  int jcol = tid & 255, half = tid >> 8;
  const int* msrc = sSrc + half * 32;
  float hv[32];
#pragma unroll
  for (int m = 0; m < 32; m++) hv[m] = h[(size_t)msrc[m] * H + jcol];
  __syncthreads();  // all waves done reading sAh; smem becomes elbuf
#pragma unroll
  for (int rg = 0; rg < 4; rg++) {
#pragma unroll
    for (int r = 0; r < 4; r++) {
      int row = rg * 16 + quad * 4 + r;
#pragma unroll
      for (int cg = 0; cg < 2; cg++) {
        int j = (cg0 + cg) * 16 + lane15;
        elbuf[row * ELP + j] = acc[rg][cg][r] + bv[cg];
      }
    }
  }
  __syncthreads();
  // segment-reduced scatter: thread (half,jcol) walks its 32 dst-sorted rows.
  {
    const int* mdst = sDst + half * 32;
    float run = 0.f;
    int prev = mdst[0];
#pragma unroll
    for (int m = 0; m < 32; m++) {
      int d = mdst[m];
      float msg = fmaxf(hv[m] + elbuf[(half * 32 + m) * ELP + jcol], 0.f);
      if (d != prev) {
        atomicAdd(&agg[(size_t)prev * H + jcol], run);
        run = 0.f;
        prev = d;
      }
      run += msg;
    }
    atomicAdd(&agg[(size_t)prev * H + jcol], run);
  }
}

// Node: z=h+agg; z1=relu(z@w1+b1); z2=z1@w2+b2; LN; h += relu(LN).
// Column-slice wave decomposition: wave wv owns cols wv*64..wv*64+63 for ALL
// 64 rows (acc[4][4]) -> each B fragment feeds 4 MFMAs (was 1) and block B
// traffic drops 1 MB -> 256 KB. LN does a cross-wave reduce via LDS partials.
__global__ __launch_bounds__(256) void k_node_mfma(
    float* __restrict__ h, const float* __restrict__ agg,
    const unsigned short* __restrict__ w1Th, const unsigned short* __restrict__ w1Tl,
    const float* __restrict__ b1,
    const unsigned short* __restrict__ w2Th, const unsigned short* __restrict__ w2Tl,
    const float* __restrict__ b2,
    const float* __restrict__ lng, const float* __restrict__ lnb) {
  __shared__ __align__(16) unsigned short sAh[64 * PITCH];  // 33792 B
  __shared__ float sPartS[64][4];
  __shared__ float sPartQ[64][4];
  __shared__ float sMu[64];
  __shared__ float sRstd[64];
  int tid = threadIdx.x;
  int base = blockIdx.x * 64;
  const float4* h4 = (const float4*)(h + (size_t)base * H);
  const float4* a4 = (const float4*)(agg + (size_t)base * H);
#pragma unroll
  for (int it = 0; it < 16; it++) {  // all 64 rows (4096 float4)
    int vi = it * 256 + tid;
    int row = vi >> 6, c4 = (vi & 63) * 4;
    float4 hv = h4[vi], av = a4[vi];
    float z[4] = {hv.x + av.x, hv.y + av.y, hv.z + av.z, hv.w + av.w};
    uint2 uh;
    uh.x = (unsigned int)f2bf(z[0]) | ((unsigned int)f2bf(z[1]) << 16);
    uh.y = (unsigned int)f2bf(z[2]) | ((unsigned int)f2bf(z[3]) << 16);
    *(uint2*)&sAh[row * PITCH + c4] = uh;
  }
  __syncthreads();
  int lane = tid & 63, wv = tid >> 6;
  int lane15 = lane & 15, quad = lane >> 4;
  int col0 = wv * 64;                 // wave's 64-col slice
  const unsigned short* aph = sAh + lane15 * PITCH + quad * 8;
  // ---- GEMM1: z1 = relu(z @ w1 + b1), acc[rg][cl]
  f32x4 acc[4][4];
#pragma unroll
  for (int i = 0; i < 4; i++)
#pragma unroll
    for (int c = 0; c < 4; c++) acc[i][c] = (f32x4){0.f, 0.f, 0.f, 0.f};
  {
    const unsigned short* bph = w1Th + (size_t)(col0 + lane15) * H + quad * 8;
    const unsigned short* bpl = w1Tl + (size_t)(col0 + lane15) * H + quad * 8;
#pragma unroll
    for (int st = 0; st < 8; st++) {
      bf16x8 ah[4];
#pragma unroll
      for (int rg = 0; rg < 4; rg++)
        ah[rg] = *(const bf16x8*)(aph + rg * 16 * PITCH + st * 32);
#pragma unroll
      for (int cl = 0; cl < 4; cl++) {
        bf16x8 bhf = *(const bf16x8*)(bph + (size_t)cl * 16 * H + st * 32);
        bf16x8 blf = *(const bf16x8*)(bpl + (size_t)cl * 16 * H + st * 32);
#pragma unroll
        for (int rg = 0; rg < 4; rg++) {
          acc[rg][cl] = __builtin_amdgcn_mfma_f32_16x16x32_bf16(ah[rg], bhf, acc[rg][cl], 0, 0, 0);
          acc[rg][cl] = __builtin_amdgcn_mfma_f32_16x16x32_bf16(ah[rg], blf, acc[rg][cl], 0, 0, 0);
        }
      }
    }
  }
  float b1v[4];
#pragma unroll
  for (int cl = 0; cl < 4; cl++) b1v[cl] = b1[col0 + cl * 16 + lane15];
  __syncthreads();  // all waves done reading z
#pragma unroll
  for (int rg = 0; rg < 4; rg++)
#pragma unroll
    for (int r = 0; r < 4; r++) {
      int row = rg * 16 + quad * 4 + r;
#pragma unroll
      for (int cl = 0; cl < 4; cl++) {
        int col = col0 + cl * 16 + lane15;
        sAh[row * PITCH + col] = f2bf(fmaxf(acc[rg][cl][r] + b1v[cl], 0.f));
      }
    }
  __syncthreads();
  // ---- GEMM2: z2 = z1 @ w2 + b2, acc2[rg][cl]
  f32x4 acc2[4][4];
#pragma unroll
  for (int i = 0; i < 4; i++)
#pragma unroll
    for (int c = 0; c < 4; c++) acc2[i][c] = (f32x4){0.f, 0.f, 0.f, 0.f};
  {
    const unsigned short* bph = w2Th + (size_t)(col0 + lane15) * H + quad * 8;
    const unsigned short* bpl = w2Tl + (size_t)(col0 + lane15) * H + quad * 8;
#pragma unroll
    for (int st = 0; st < 8; st++) {
      bf16x8 ah[4];
#pragma unroll
      for (int rg = 0; rg < 4; rg++)
        ah[rg] = *(const bf16x8*)(aph + rg * 16 * PITCH + st * 32);
#pragma unroll
      for (int cl = 0; cl < 4; cl++) {
        bf16x8 bhf = *(const bf16x8*)(bph + (size_t)cl * 16 * H + st * 32);
        bf16x8 blf = *(const bf16x8*)(bpl + (size_t)cl * 16 * H + st * 32);
#pragma unroll
        for (int rg = 0; rg < 4; rg++) {
          acc2[rg][cl] = __builtin_amdgcn_mfma_f32_16x16x32_bf16(ah[rg], bhf, acc2[rg][cl], 0, 0, 0);
          acc2[rg][cl] = __builtin_amdgcn_mfma_f32_16x16x32_bf16(ah[rg], blf, acc2[rg][cl], 0, 0, 0);
        }
      }
    }
  }
  float b2v[4], gv[4], bbv[4];
#pragma unroll
  for (int cl = 0; cl < 4; cl++) {
    int col = col0 + cl * 16 + lane15;
    b2v[cl] = b2[col]; gv[cl] = lng[col]; bbv[cl] = lnb[col];
  }
  // ---- LN partials: per row, reduce this wave's 64 cols
#pragma unroll
  for (int rg = 0; rg < 4; rg++)
#pragma unroll
    for (int r = 0; r < 4; r++) {
      int row = rg * 16 + quad * 4 + r;
      float s = 0.f, ss = 0.f;
#pragma unroll
      for (int cl = 0; cl < 4; cl++) {
        float z2 = acc2[rg][cl][r] + b2v[cl];
        s += z2;
        ss = fmaf(z2, z2, ss);
      }
      s += __shfl_xor(s, 1, 64); ss += __shfl_xor(ss, 1, 64);
      s += __shfl_xor(s, 2, 64); ss += __shfl_xor(ss, 2, 64);
      s += __shfl_xor(s, 4, 64); ss += __shfl_xor(ss, 4, 64);
      s += __shfl_xor(s, 8, 64); ss += __shfl_xor(ss, 8, 64);
      if (lane15 == 0) { sPartS[row][wv] = s; sPartQ[row][wv] = ss; }
    }
  __syncthreads();
  if (tid < 64) {
    float s = sPartS[tid][0] + sPartS[tid][1] + sPartS[tid][2] + sPartS[tid][3];
    float ss = sPartQ[tid][0] + sPartQ[tid][1] + sPartQ[tid][2] + sPartQ[tid][3];
    float mu = s * (1.f / H);
    float var = ss * (1.f / H) - mu * mu;
    sMu[tid] = mu;
    sRstd[tid] = rsqrtf(var + LN_EPS);
  }
  __syncthreads();
  // ---- apply LN + residual
#pragma unroll
  for (int rg = 0; rg < 4; rg++)
#pragma unroll
    for (int r = 0; r < 4; r++) {
      int row = rg * 16 + quad * 4 + r;
      float mu = sMu[row], rstd = sRstd[row];
      float* hr = h + (size_t)(base + row) * H;
#pragma unroll
      for (int cl = 0; cl < 4; cl++) {
        int col = col0 + cl * 16 + lane15;
        float z2 = acc2[rg][cl][r] + b2v[cl];
        float v = fmaf((z2 - mu) * rstd, gv[cl], bbv[cl]);
        hr[col] = hr[col] + fmaxf(v, 0.f);
      }
    }
}

// Partial mean-pool: block sums 64 rows into g[b][.] via atomics (fully parallel).
__global__ __launch_bounds__(256) void k_pool(
    const float* __restrict__ h, float* __restrict__ g, int n) {
  int tid = threadIdx.x;
  int row0 = blockIdx.x * 64;
  int b = row0 / n;                       // 64 | n, block never straddles graphs
  const float* hb = h + (size_t)row0 * H;
  float s0 = 0.f, s1 = 0.f, s2 = 0.f, s3 = 0.f;
  for (int i = 0; i < 64; i += 4) {
    s0 += hb[(size_t)(i + 0) * H + tid];
    s1 += hb[(size_t)(i + 1) * H + tid];
    s2 += hb[(size_t)(i + 2) * H + tid];
    s3 += hb[(size_t)(i + 3) * H + tid];
  }
  atomicAdd(&g[(size_t)b * H + tid], s0 + s1 + s2 + s3);
}

// Head MLP from pooled g. One block per graph.
__global__ __launch_bounds__(256) void k_head(
    const float* __restrict__ g,
    const float* __restrict__ w1, const float* __restrict__ b1,
    const float* __restrict__ w2, const float* __restrict__ b2,
    float* __restrict__ out, int n) {
  __shared__ float sG[H];
  __shared__ float sT[H];
  __shared__ float sR[4];
  int b = blockIdx.x, tid = threadIdx.x;
  sG[tid] = g[(size_t)b * H + tid] / (float)n;
  __syncthreads();
  float t = b1[tid];
  for (int k = 0; k < H; k++) t = fmaf(sG[k], w1[k * H + tid], t);
  sT[tid] = fmaxf(t, 0.f);
  __syncthreads();
  float p = sT[tid] * w2[tid];
#pragma unroll
  for (int off = 32; off > 0; off >>= 1) p += __shfl_xor(p, off, 64);
  if ((tid & 63) == 0) sR[tid >> 6] = p;
  __syncthreads();
  if (tid == 0) out[b] = sR[0] + sR[1] + sR[2] + sR[3] + b2[0];
}

// ---------- launcher ----------
extern "C" void kernel_launch(void* const* d_in, const int* in_sizes, int n_in,
                              void* d_out, int out_size, void* d_ws, size_t ws_size,
                              hipStream_t stream) {
  const float* x      = (const float*)d_in[0];
  const float* ea     = (const float*)d_in[1];
  const void*  ei     = d_in[2];
  const int*   a      = (const int*)d_in[3];
  const float* np_w   = (const float*)d_in[4];
  const float* np_b   = (const float*)d_in[5];
  const float* em_w1  = (const float*)d_in[6];
  const float* em_b1  = (const float*)d_in[7];
  const float* em_w2  = (const float*)d_in[8];
  const float* em_b2  = (const float*)d_in[9];
  const float* lin_w  = (const float*)d_in[10];
  const float* lin_b  = (const float*)d_in[11];
  const float* m_w1   = (const float*)d_in[12];
  const float* m_b1   = (const float*)d_in[13];
  const float* m_w2   = (const float*)d_in[14];
  const float* m_b2   = (const float*)d_in[15];
  const float* ln_g   = (const float*)d_in[16];
  const float* ln_b   = (const float*)d_in[17];
  const float* hd_w1  = (const float*)d_in[18];
  const float* hd_b1  = (const float*)d_in[19];
  const float* hd_w2  = (const float*)d_in[20];
  const float* hd_b2  = (const float*)d_in[21];

  int N = in_sizes[0] / 3;
  int E = in_sizes[1] / 4;
  int B = out_size;
  int n = N / B;

  // workspace layout (~82 MB)
  char* ws = (char*)d_ws;
  size_t off = 0;
  auto alloc = [&](size_t bytes) {
    char* p = ws + off;
    off += (bytes + 255) & ~(size_t)255;
    return p;
  };
  float* h    = (float*)alloc((size_t)N * H * 4);
  float* agg  = (float*)alloc((size_t)N * H * 4);
  unsigned short* wcTh = (unsigned short*)alloc((size_t)3 * H * H * 2);
  unsigned short* wcTl = (unsigned short*)alloc((size_t)3 * H * H * 2);
  unsigned short* w1Th = (unsigned short*)alloc((size_t)3 * H * H * 2);
  unsigned short* w1Tl = (unsigned short*)alloc((size_t)3 * H * H * 2);
  unsigned short* w2Th = (unsigned short*)alloc((size_t)3 * H * H * 2);
  unsigned short* w2Tl = (unsigned short*)alloc((size_t)3 * H * H * 2);
  float* beta  = (float*)alloc(3 * H * 4);
  int*   flag  = (int*)alloc(4);
  int*   hist  = (int*)alloc((size_t)N * 4);
  int*   curs  = (int*)alloc((size_t)N * 4);
  int*   srcS  = (int*)alloc((size_t)E * 4);
  int*   dstS  = (int*)alloc((size_t)E * 4);
  float* eaS   = (float*)alloc((size_t)E * 4 * 4);
  float* g     = (float*)alloc((size_t)B * H * 4);

  float* out = (float*)d_out;
  int ebl = (E + 255) / 256;

  k_detect<<<1, 64, 0, stream>>>((const int*)ei, flag);
  k_zero<<<(N + 1023) / 1024, 256, 0, stream>>>((float4*)hist, N / 4);
  k_hist<<<ebl, 256, 0, stream>>>(ei, flag, hist, E);
  k_scan<<<1, 256, 0, stream>>>(hist, curs, N);
  k_scatter<<<ebl, 256, 0, stream>>>(ei, flag, ea, curs, srcS, dstS, eaS, E);
  k_node_proj<<<N, 256, 0, stream>>>(x, a, np_w, np_b, h, N);
  k_wcomb<<<24, 256, 0, stream>>>(em_w2, lin_w, wcTh, wcTl);
  k_beta<<<3, 256, 0, stream>>>(lin_w, lin_b, em_b2, beta);
  k_transp<<<dim3(4, 4, 3), 256, 0, stream>>>(m_w1, w1Th, w1Tl);
  k_transp<<<dim3(4, 4, 3), 256, 0, stream>>>(m_w2, w2Th, w2Tl);

  int n4 = N * H / 4;
  for (int l = 0; l < 3; l++) {
    k_zero<<<(n4 + 255) / 256, 256, 0, stream>>>((float4*)agg, n4);
    k_edge_mfma<<<E / TE, 512, 0, stream>>>(eaS, em_w1, em_b1,
                                            wcTh + (size_t)l * H * H,
                                            wcTl + (size_t)l * H * H,
                                            beta + (size_t)l * H,
                                            h, agg, srcS, dstS);
    k_node_mfma<<<N / 64, 256, 0, stream>>>(h, agg,
                                            w1Th + (size_t)l * H * H,
                                            w1Tl + (size_t)l * H * H,
                                            m_b1 + (size_t)l * H,
                                            w2Th + (size_t)l * H * H,
                                            w2Tl + (size_t)l * H * H,
                                            m_b2 + (size_t)l * H,
                                            ln_g + (size_t)l * H, ln_b + (size_t)l * H);
  }
  int g4 = B * H / 4;
  k_zero<<<(g4 + 255) / 256, 256, 0, stream>>>((float4*)g, g4);
  k_pool<<<N / 64, 256, 0, stream>>>(h, g, n);
  k_head<<<B, 256, 0, stream>>>(g, hd_w1, hd_b1, hd_w2, hd_b2, out, n);
}

// Round 5
// 1011.738 us; speedup vs baseline: 1.9204x; 1.0538x over previous
//
#include <hip/hip_runtime.h>
#include <hip/hip_bf16.h>

#define H 256
#define LN_EPS 1e-5f
#define PITCH 264   // bf16 elements per LDS A-row (256 + 8 pad), 528 B
#define TE 64       // edges per tile (edge kernel)

typedef __attribute__((ext_vector_type(8))) short bf16x8;   // 8 bf16 = 4 VGPRs
typedef __attribute__((ext_vector_type(4))) float f32x4;    // MFMA 16x16 accum

// ---------- helpers ----------
__device__ __forceinline__ float bf2f(unsigned short u) {
  union { unsigned int i; float f; } v; v.i = ((unsigned int)u) << 16; return v.f;
}
__device__ __forceinline__ unsigned short f2bf(float f) {
  union { float f; unsigned int i; } v; v.f = f;
  unsigned int x = v.i;
  return (unsigned short)((x + 0x7fffu + ((x >> 16) & 1u)) >> 16);  // RNE
}
__device__ __forceinline__ void fsplit(float v, unsigned short& hi, unsigned short& lo) {
  hi = f2bf(v);
  lo = f2bf(v - bf2f(hi));
}

// fp32 register-tiled GEMM core (precompute only)
__device__ __forceinline__ void gemm_tile(const float* __restrict__ sA,
                                          const float* __restrict__ W,
                                          int lane_j, int rg, float acc[8][4]) {
#pragma unroll
  for (int mm = 0; mm < 8; mm++)
#pragma unroll
    for (int cc = 0; cc < 4; cc++) acc[mm][cc] = 0.f;
  for (int k = 0; k < H; k += 4) {
    float tvf[8][4];
#pragma unroll
    for (int mm = 0; mm < 8; mm++)
      *(float4*)&tvf[mm][0] = *(const float4*)&sA[(rg * 8 + mm) * H + k];
#pragma unroll
    for (int kk = 0; kk < 4; kk++) {
      const float* wr = W + (k + kk) * H + lane_j;
      float w0 = wr[0], w1 = wr[64], w2 = wr[128], w3 = wr[192];
#pragma unroll
      for (int mm = 0; mm < 8; mm++) {
        float av = tvf[mm][kk];
        acc[mm][0] = fmaf(av, w0, acc[mm][0]);
        acc[mm][1] = fmaf(av, w1, acc[mm][1]);
        acc[mm][2] = fmaf(av, w2, acc[mm][2]);
        acc[mm][3] = fmaf(av, w3, acc[mm][3]);
      }
    }
  }
}

// ---------- precompute kernels ----------

__global__ void k_detect(const int* __restrict__ ei, int* __restrict__ flag) {
  if (threadIdx.x == 0 && blockIdx.x == 0)
    *flag = (ei[1] == 0 && ei[3] == 0 && ei[5] == 0 && ei[7] == 0) ? 1 : 0;
}

__global__ __launch_bounds__(256) void k_zero(float4* __restrict__ p, int n4) {
  int i = blockIdx.x * 256 + threadIdx.x;
  if (i < n4) p[i] = make_float4(0.f, 0.f, 0.f, 0.f);
}

// dst histogram
__global__ __launch_bounds__(256) void k_hist(
    const void* __restrict__ ei, const int* __restrict__ flag64,
    int* __restrict__ hist, int E) {
  int e = blockIdx.x * 256 + threadIdx.x;
  if (e >= E) return;
  int d = (*flag64) ? (int)((const long long*)ei)[(size_t)E + e]
                    : ((const int*)ei)[(size_t)E + e];
  atomicAdd(&hist[d], 1);
}

// exclusive prefix sum over hist[N] -> cursor[N] (single block, 256 threads)
__global__ __launch_bounds__(256) void k_scan(
    const int* __restrict__ hist, int* __restrict__ cursor, int N) {
  __shared__ int part[256];
  int tid = threadIdx.x;
  int chunk = (N + 255) / 256;
  int s = 0;
  for (int i = 0; i < chunk; i++) {
    int idx = tid * chunk + i;
    if (idx < N) s += hist[idx];
  }
  part[tid] = s;
  __syncthreads();
  for (int off = 1; off < 256; off <<= 1) {
    int v = (tid >= off) ? part[tid - off] : 0;
    __syncthreads();
    part[tid] += v;
    __syncthreads();
  }
  int excl = (tid == 0) ? 0 : part[tid - 1];
  for (int i = 0; i < chunk; i++) {
    int idx = tid * chunk + i;
    if (idx < N) {
      cursor[idx] = excl;
      excl += hist[idx];
    }
  }
}

// scatter edges into dst-sorted order (src, dst, edge_attr)
__global__ __launch_bounds__(256) void k_scatter(
    const void* __restrict__ ei, const int* __restrict__ flag64,
    const float* __restrict__ ea, int* __restrict__ cursor,
    int* __restrict__ srcS, int* __restrict__ dstS, float* __restrict__ eaS, int E) {
  int e = blockIdx.x * 256 + threadIdx.x;
  if (e >= E) return;
  int is64 = *flag64;
  int s = is64 ? (int)((const long long*)ei)[e] : ((const int*)ei)[e];
  int d = is64 ? (int)((const long long*)ei)[(size_t)E + e]
               : ((const int*)ei)[(size_t)E + e];
  int p = atomicAdd(&cursor[d], 1);
  srcS[p] = s;
  dstS[p] = d;
  ((float4*)eaS)[p] = ((const float4*)ea)[e];
}

__global__ __launch_bounds__(256) void k_node_proj(
    const float* __restrict__ x, const int* __restrict__ a,
    const float* __restrict__ w, const float* __restrict__ b,
    float* __restrict__ h, int N) {
  int node = blockIdx.x;
  int j = threadIdx.x;
  float acc = b[j];
  acc = fmaf(x[node * 3 + 0], w[0 * H + j], acc);
  acc = fmaf(x[node * 3 + 1], w[1 * H + j], acc);
  acc = fmaf(x[node * 3 + 2], w[2 * H + j], acc);
  acc = fmaf((float)a[node], w[3 * H + j], acc);
  h[(size_t)node * H + j] = fmaxf(acc, 0.f);
}

// WtC[l][j][k] = (em_w2 @ lin_w[l])[k][j], hi/lo bf16 planes
__global__ __launch_bounds__(256, 2) void k_wcomb(
    const float* __restrict__ w2, const float* __restrict__ lin_w,
    unsigned short* __restrict__ wcTh, unsigned short* __restrict__ wcTl) {
  __shared__ __align__(16) float sA[32 * H];
  int l = blockIdx.x >> 3, tile = blockIdx.x & 7;
  int tid = threadIdx.x;
  const float4* src = (const float4*)(w2 + (size_t)tile * 32 * H);
#pragma unroll
  for (int it = 0; it < 8; it++) {
    int vi = it * 256 + tid;
    *(float4*)&sA[vi * 4] = src[vi];
  }
  __syncthreads();
  int lane_j = tid & 63, rg = tid >> 6;
  float acc[8][4];
  gemm_tile(sA, lin_w + (size_t)l * H * H, lane_j, rg, acc);
  unsigned short* oh = wcTh + (size_t)l * H * H;
  unsigned short* ol = wcTl + (size_t)l * H * H;
#pragma unroll
  for (int cc = 0; cc < 4; cc++) {
    int j = lane_j + 64 * cc;
#pragma unroll
    for (int mm = 0; mm < 8; mm++) {
      int k = tile * 32 + rg * 8 + mm;
      unsigned short hi, lo;
      fsplit(acc[mm][cc], hi, lo);
      oh[(size_t)j * H + k] = hi;
      ol[(size_t)j * H + k] = lo;
    }
  }
}

// beta[l] = em_b2 @ lin_w[l] + lin_b[l]
__global__ __launch_bounds__(256) void k_beta(
    const float* __restrict__ lin_w, const float* __restrict__ lin_b,
    const float* __restrict__ b2, float* __restrict__ beta) {
  int l = blockIdx.x, j = threadIdx.x;
  const float* W = lin_w + (size_t)l * H * H;
  float v = lin_b[l * H + j];
  for (int k = 0; k < H; k++) v = fmaf(b2[k], W[k * H + j], v);
  beta[l * H + j] = v;
}

// out_{h,l}[l][n][k] = bf16split(in[l][k][n])
__global__ __launch_bounds__(256) void k_transp(
    const float* __restrict__ in,
    unsigned short* __restrict__ outh, unsigned short* __restrict__ outl) {
  int l = blockIdx.z;
  int kb = blockIdx.x * 64, nb = blockIdx.y * 64;
  int tid = threadIdx.x;
  __shared__ float T[64][65];
  const float* src = in + (size_t)l * H * H;
#pragma unroll
  for (int it = 0; it < 16; it++) {
    int idx = it * 256 + tid;
    int kl = idx >> 6, nl = idx & 63;
    T[kl][nl] = src[(size_t)(kb + kl) * H + nb + nl];
  }
  __syncthreads();
  unsigned short* dh = outh + (size_t)l * H * H;
  unsigned short* dl = outl + (size_t)l * H * H;
#pragma unroll
  for (int it = 0; it < 8; it++) {
    int u = it * 256 + tid;
    int nl = u >> 5, k2 = (u & 31) * 2;
    unsigned short h0, l0, h1, l1;
    fsplit(T[k2][nl], h0, l0);
    fsplit(T[k2 + 1][nl], h1, l1);
    size_t o = (size_t)(nb + nl) * H + kb + k2;
    *(unsigned int*)&dh[o] = (unsigned int)h0 | ((unsigned int)h1 << 16);
    *(unsigned int*)&dl[o] = (unsigned int)l0 | ((unsigned int)l1 << 16);
  }
}

// ---------- per-layer MFMA kernels ----------

// Edge (dst-sorted), tile = TE(64) edges x 256 cols, 8 waves.
// A hi-plane only, B hi-plane only: e_l = A_hi * B_hi (64 MFMA/wave).
// elbuf is BF16 and aliases the A-tile exactly (64 x PITCH shorts = 33.8 KB)
// -> total LDS ~35.3 KB -> 3 blocks/CU (regs: 52 arch + 32 acc = 84 <= 85).
// launch_bounds min-waves MUST stay 4 (128-reg cap; 8 caused R2 spill storm).
__global__ __launch_bounds__(512, 4) void k_edge_mfma(
    const float* __restrict__ eaS,
    const float* __restrict__ w1, const float* __restrict__ b1,
    const unsigned short* __restrict__ Wth, const unsigned short* __restrict__ Wtl,
    const float* __restrict__ beta,
    const float* __restrict__ h, float* __restrict__ agg,
    const int* __restrict__ srcS, const int* __restrict__ dstS) {
  __shared__ __align__(16) unsigned short sAh[TE * PITCH];  // 33792 B, A-tile / bf16 elbuf
  __shared__ __align__(16) float sEA[TE * 4];
  __shared__ int sSrc[TE];
  __shared__ int sDst[TE];
  int tid = threadIdx.x;
  int base = blockIdx.x * TE;
  if (tid < TE) {
    sSrc[tid] = srcS[base + tid];
  } else if (tid < 2 * TE) {
    sDst[tid - TE] = dstS[base + tid - TE];
  } else if (tid < 3 * TE) {
    int t = tid - 2 * TE;
    ((float4*)sEA)[t] = ((const float4*)(eaS + (size_t)base * 4))[t];
  }
  __syncthreads();
  {  // t = relu(eaS @ w1 + b1) -> bf16 hi plane only (col pair, 16 rows/thread)
    int j2 = (tid & 127) * 2;
    int r0 = (tid >> 7) * 16;
    float wv0[4], wv1[4];
#pragma unroll
    for (int q = 0; q < 4; q++) { wv0[q] = w1[q * H + j2]; wv1[q] = w1[q * H + j2 + 1]; }
    float bb0 = b1[j2], bb1 = b1[j2 + 1];
#pragma unroll
    for (int m = r0; m < r0 + 16; m++) {
      float t0 = bb0, t1 = bb1;
#pragma unroll
      for (int q = 0; q < 4; q++) {
        float eav = sEA[m * 4 + q];
        t0 = fmaf(eav, wv0[q], t0);
        t1 = fmaf(eav, wv1[q], t1);
      }
      t0 = fmaxf(t0, 0.f); t1 = fmaxf(t1, 0.f);
      *(unsigned int*)&sAh[m * PITCH + j2] =
          (unsigned int)f2bf(t0) | ((unsigned int)f2bf(t1) << 16);
    }
  }
  __syncthreads();
  int lane = tid & 63, wv = tid >> 6;           // wv in 0..7
  int lane15 = lane & 15, quad = lane >> 4;
  int cg0 = wv * 2;                             // wave's 2 col-groups (32 cols)
  f32x4 acc[4][2];
#pragma unroll
  for (int i = 0; i < 4; i++)
#pragma unroll
    for (int c = 0; c < 2; c++) acc[i][c] = (f32x4){0.f, 0.f, 0.f, 0.f};
  const unsigned short* aph = sAh + lane15 * PITCH + quad * 8;
  const unsigned short* bph = Wth + (size_t)(cg0 * 16 + lane15) * H + quad * 8;
#pragma unroll
  for (int st = 0; st < 8; st++) {
    bf16x8 ah[4];
#pragma unroll
    for (int rg = 0; rg < 4; rg++)
      ah[rg] = *(const bf16x8*)(aph + rg * 16 * PITCH + st * 32);
#pragma unroll
    for (int cg = 0; cg < 2; cg++) {
      bf16x8 bhf = *(const bf16x8*)(bph + (size_t)cg * 16 * H + st * 32);
#pragma unroll
      for (int rg = 0; rg < 4; rg++)
        acc[rg][cg] = __builtin_amdgcn_mfma_f32_16x16x32_bf16(ah[rg], bhf, acc[rg][cg], 0, 0, 0);
    }
  }
  float bv[2];
#pragma unroll
  for (int cg = 0; cg < 2; cg++) bv[cg] = beta[(cg0 + cg) * 16 + lane15];
  // h-gather: issue before the A-done barrier; loads stay in flight across it.
  int jcol = tid & 255, half = tid >> 8;
  const int* msrc = sSrc + half * 32;
  float hv[32];
#pragma unroll
  for (int m = 0; m < 32; m++) hv[m] = h[(size_t)msrc[m] * H + jcol];
  __syncthreads();  // all waves done reading A; sAh becomes bf16 elbuf
#pragma unroll
  for (int rg = 0; rg < 4; rg++) {
#pragma unroll
    for (int r = 0; r < 4; r++) {
      int row = rg * 16 + quad * 4 + r;
#pragma unroll
      for (int cg = 0; cg < 2; cg++) {
        int j = (cg0 + cg) * 16 + lane15;
        sAh[row * PITCH + j] = f2bf(acc[rg][cg][r] + bv[cg]);
      }
    }
  }
  __syncthreads();
  // segment-reduced scatter: thread (half,jcol) walks its 32 dst-sorted rows.
  {
    const int* mdst = sDst + half * 32;
    float run = 0.f;
    int prev = mdst[0];
#pragma unroll
    for (int m = 0; m < 32; m++) {
      int d = mdst[m];
      float msg = fmaxf(hv[m] + bf2f(sAh[(half * 32 + m) * PITCH + jcol]), 0.f);
      if (d != prev) {
        atomicAdd(&agg[(size_t)prev * H + jcol], run);
        run = 0.f;
        prev = d;
      }
      run += msg;
    }
    atomicAdd(&agg[(size_t)prev * H + jcol], run);
  }
}

// Node: z=h+agg; z1=relu(z@w1+b1); z2=z1@w2+b2; LN; h += relu(LN).
// Column-slice wave decomposition (wave owns 64 cols x all 64 rows).
// A single bf16 plane AND B single bf16 plane (hi only) on both GEMMs.
__global__ __launch_bounds__(256) void k_node_mfma(
    float* __restrict__ h, const float* __restrict__ agg,
    const unsigned short* __restrict__ w1Th, const float* __restrict__ b1,
    const unsigned short* __restrict__ w2Th, const float* __restrict__ b2,
    const float* __restrict__ lng, const float* __restrict__ lnb) {
  __shared__ __align__(16) unsigned short sAh[64 * PITCH];  // 33792 B
  __shared__ float sPartS[64][4];
  __shared__ float sPartQ[64][4];
  __shared__ float sMu[64];
  __shared__ float sRstd[64];
  int tid = threadIdx.x;
  int base = blockIdx.x * 64;
  const float4* h4 = (const float4*)(h + (size_t)base * H);
  const float4* a4 = (const float4*)(agg + (size_t)base * H);
#pragma unroll
  for (int it = 0; it < 16; it++) {  // all 64 rows (4096 float4)
    int vi = it * 256 + tid;
    int row = vi >> 6, c4 = (vi & 63) * 4;
    float4 hv = h4[vi], av = a4[vi];
    float z[4] = {hv.x + av.x, hv.y + av.y, hv.z + av.z, hv.w + av.w};
    uint2 uh;
    uh.x = (unsigned int)f2bf(z[0]) | ((unsigned int)f2bf(z[1]) << 16);
    uh.y = (unsigned int)f2bf(z[2]) | ((unsigned int)f2bf(z[3]) << 16);
    *(uint2*)&sAh[row * PITCH + c4] = uh;
  }
  __syncthreads();
  int lane = tid & 63, wv = tid >> 6;
  int lane15 = lane & 15, quad = lane >> 4;
  int col0 = wv * 64;                 // wave's 64-col slice
  const unsigned short* aph = sAh + lane15 * PITCH + quad * 8;
  // ---- GEMM1: z1 = relu(z @ w1 + b1), acc[rg][cl]
  f32x4 acc[4][4];
#pragma unroll
  for (int i = 0; i < 4; i++)
#pragma unroll
    for (int c = 0; c < 4; c++) acc[i][c] = (f32x4){0.f, 0.f, 0.f, 0.f};
  {
    const unsigned short* bph = w1Th + (size_t)(col0 + lane15) * H + quad * 8;
#pragma unroll
    for (int st = 0; st < 8; st++) {
      bf16x8 ah[4];
#pragma unroll
      for (int rg = 0; rg < 4; rg++)
        ah[rg] = *(const bf16x8*)(aph + rg * 16 * PITCH + st * 32);
#pragma unroll
      for (int cl = 0; cl < 4; cl++) {
        bf16x8 bhf = *(const bf16x8*)(bph + (size_t)cl * 16 * H + st * 32);
#pragma unroll
        for (int rg = 0; rg < 4; rg++)
          acc[rg][cl] = __builtin_amdgcn_mfma_f32_16x16x32_bf16(ah[rg], bhf, acc[rg][cl], 0, 0, 0);
      }
    }
  }
  float b1v[4];
#pragma unroll
  for (int cl = 0; cl < 4; cl++) b1v[cl] = b1[col0 + cl * 16 + lane15];
  __syncthreads();  // all waves done reading z
#pragma unroll
  for (int rg = 0; rg < 4; rg++)
#pragma unroll
    for (int r = 0; r < 4; r++) {
      int row = rg * 16 + quad * 4 + r;
#pragma unroll
      for (int cl = 0; cl < 4; cl++) {
        int col = col0 + cl * 16 + lane15;
        sAh[row * PITCH + col] = f2bf(fmaxf(acc[rg][cl][r] + b1v[cl], 0.f));
      }
    }
  __syncthreads();
  // ---- GEMM2: z2 = z1 @ w2 + b2, acc2[rg][cl]
  f32x4 acc2[4][4];
#pragma unroll
  for (int i = 0; i < 4; i++)
#pragma unroll
    for (int c = 0; c < 4; c++) acc2[i][c] = (f32x4){0.f, 0.f, 0.f, 0.f};
  {
    const unsigned short* bph = w2Th + (size_t)(col0 + lane15) * H + quad * 8;
#pragma unroll
    for (int st = 0; st < 8; st++) {
      bf16x8 ah[4];
#pragma unroll
      for (int rg = 0; rg < 4; rg++)
        ah[rg] = *(const bf16x8*)(aph + rg * 16 * PITCH + st * 32);
#pragma unroll
      for (int cl = 0; cl < 4; cl++) {
        bf16x8 bhf = *(const bf16x8*)(bph + (size_t)cl * 16 * H + st * 32);
#pragma unroll
        for (int rg = 0; rg < 4; rg++)
          acc2[rg][cl] = __builtin_amdgcn_mfma_f32_16x16x32_bf16(ah[rg], bhf, acc2[rg][cl], 0, 0, 0);
      }
    }
  }
  float b2v[4], gv[4], bbv[4];
#pragma unroll
  for (int cl = 0; cl < 4; cl++) {
    int col = col0 + cl * 16 + lane15;
    b2v[cl] = b2[col]; gv[cl] = lng[col]; bbv[cl] = lnb[col];
  }
  // ---- LN partials: per row, reduce this wave's 64 cols
#pragma unroll
  for (int rg = 0; rg < 4; rg++)
#pragma unroll
    for (int r = 0; r < 4; r++) {
      int row = rg * 16 + quad * 4 + r;
      float s = 0.f, ss = 0.f;
#pragma unroll
      for (int cl = 0; cl < 4; cl++) {
        float z2 = acc2[rg][cl][r] + b2v[cl];
        s += z2;
        ss = fmaf(z2, z2, ss);
      }
      s += __shfl_xor(s, 1, 64); ss += __shfl_xor(ss, 1, 64);
      s += __shfl_xor(s, 2, 64); ss += __shfl_xor(ss, 2, 64);
      s += __shfl_xor(s, 4, 64); ss += __shfl_xor(ss, 4, 64);
      s += __shfl_xor(s, 8, 64); ss += __shfl_xor(ss, 8, 64);
      if (lane15 == 0) { sPartS[row][wv] = s; sPartQ[row][wv] = ss; }
    }
  __syncthreads();
  if (tid < 64) {
    float s = sPartS[tid][0] + sPartS[tid][1] + sPartS[tid][2] + sPartS[tid][3];
    float ss = sPartQ[tid][0] + sPartQ[tid][1] + sPartQ[tid][2] + sPartQ[tid][3];
    float mu = s * (1.f / H);
    float var = ss * (1.f / H) - mu * mu;
    sMu[tid] = mu;
    sRstd[tid] = rsqrtf(var + LN_EPS);
  }
  __syncthreads();
  // ---- apply LN + residual
#pragma unroll
  for (int rg = 0; rg < 4; rg++)
#pragma unroll
    for (int r = 0; r < 4; r++) {
      int row = rg * 16 + quad * 4 + r;
      float mu = sMu[row], rstd = sRstd[row];
      float* hr = h + (size_t)(base + row) * H;
#pragma unroll
      for (int cl = 0; cl < 4; cl++) {
        int col = col0 + cl * 16 + lane15;
        float z2 = acc2[rg][cl][r] + b2v[cl];
        float v = fmaf((z2 - mu) * rstd, gv[cl], bbv[cl]);
        hr[col] = hr[col] + fmaxf(v, 0.f);
      }
    }
}

// Partial mean-pool: block sums 64 rows into g[b][.] via atomics (fully parallel).
__global__ __launch_bounds__(256) void k_pool(
    const float* __restrict__ h, float* __restrict__ g, int n) {
  int tid = threadIdx.x;
  int row0 = blockIdx.x * 64;
  int b = row0 / n;                       // 64 | n, block never straddles graphs
  const float* hb = h + (size_t)row0 * H;
  float s0 = 0.f, s1 = 0.f, s2 = 0.f, s3 = 0.f;
  for (int i = 0; i < 64; i += 4) {
    s0 += hb[(size_t)(i + 0) * H + tid];
    s1 += hb[(size_t)(i + 1) * H + tid];
    s2 += hb[(size_t)(i + 2) * H + tid];
    s3 += hb[(size_t)(i + 3) * H + tid];
  }
  atomicAdd(&g[(size_t)b * H + tid], s0 + s1 + s2 + s3);
}

// Head MLP from pooled g. One block per graph.
__global__ __launch_bounds__(256) void k_head(
    const float* __restrict__ g,
    const float* __restrict__ w1, const float* __restrict__ b1,
    const float* __restrict__ w2, const float* __restrict__ b2,
    float* __restrict__ out, int n) {
  __shared__ float sG[H];
  __shared__ float sT[H];
  __shared__ float sR[4];
  int b = blockIdx.x, tid = threadIdx.x;
  sG[tid] = g[(size_t)b * H + tid] / (float)n;
  __syncthreads();
  float t = b1[tid];
  for (int k = 0; k < H; k++) t = fmaf(sG[k], w1[k * H + tid], t);
  sT[tid] = fmaxf(t, 0.f);
  __syncthreads();
  float p = sT[tid] * w2[tid];
#pragma unroll
  for (int off = 32; off > 0; off >>= 1) p += __shfl_xor(p, off, 64);
  if ((tid & 63) == 0) sR[tid >> 6] = p;
  __syncthreads();
  if (tid == 0) out[b] = sR[0] + sR[1] + sR[2] + sR[3] + b2[0];
}

// ---------- launcher ----------
extern "C" void kernel_launch(void* const* d_in, const int* in_sizes, int n_in,
                              void* d_out, int out_size, void* d_ws, size_t ws_size,
                              hipStream_t stream) {
  const float* x      = (const float*)d_in[0];
  const float* ea     = (const float*)d_in[1];
  const void*  ei     = d_in[2];
  const int*   a      = (const int*)d_in[3];
  const float* np_w   = (const float*)d_in[4];
  const float* np_b   = (const float*)d_in[5];
  const float* em_w1  = (const float*)d_in[6];
  const float* em_b1  = (const float*)d_in[7];
  const float* em_w2  = (const float*)d_in[8];
  const float* em_b2  = (const float*)d_in[9];
  const float* lin_w  = (const float*)d_in[10];
  const float* lin_b  = (const float*)d_in[11];
  const float* m_w1   = (const float*)d_in[12];
  const float* m_b1   = (const float*)d_in[13];
  const float* m_w2   = (const float*)d_in[14];
  const float* m_b2   = (const float*)d_in[15];
  const float* ln_g   = (const float*)d_in[16];
  const float* ln_b   = (const float*)d_in[17];
  const float* hd_w1  = (const float*)d_in[18];
  const float* hd_b1  = (const float*)d_in[19];
  const float* hd_w2  = (const float*)d_in[20];
  const float* hd_b2  = (const float*)d_in[21];

  int N = in_sizes[0] / 3;
  int E = in_sizes[1] / 4;
  int B = out_size;
  int n = N / B;

  // workspace layout (~82 MB)
  char* ws = (char*)d_ws;
  size_t off = 0;
  auto alloc = [&](size_t bytes) {
    char* p = ws + off;
    off += (bytes + 255) & ~(size_t)255;
    return p;
  };
  float* h    = (float*)alloc((size_t)N * H * 4);
  float* agg  = (float*)alloc((size_t)N * H * 4);
  unsigned short* wcTh = (unsigned short*)alloc((size_t)3 * H * H * 2);
  unsigned short* wcTl = (unsigned short*)alloc((size_t)3 * H * H * 2);
  unsigned short* w1Th = (unsigned short*)alloc((size_t)3 * H * H * 2);
  unsigned short* w1Tl = (unsigned short*)alloc((size_t)3 * H * H * 2);
  unsigned short* w2Th = (unsigned short*)alloc((size_t)3 * H * H * 2);
  unsigned short* w2Tl = (unsigned short*)alloc((size_t)3 * H * H * 2);
  float* beta  = (float*)alloc(3 * H * 4);
  int*   flag  = (int*)alloc(4);
  int*   hist  = (int*)alloc((size_t)N * 4);
  int*   curs  = (int*)alloc((size_t)N * 4);
  int*   srcS  = (int*)alloc((size_t)E * 4);
  int*   dstS  = (int*)alloc((size_t)E * 4);
  float* eaS   = (float*)alloc((size_t)E * 4 * 4);
  float* g     = (float*)alloc((size_t)B * H * 4);

  float* out = (float*)d_out;
  int ebl = (E + 255) / 256;

  k_detect<<<1, 64, 0, stream>>>((const int*)ei, flag);
  k_zero<<<(N + 1023) / 1024, 256, 0, stream>>>((float4*)hist, N / 4);
  k_hist<<<ebl, 256, 0, stream>>>(ei, flag, hist, E);
  k_scan<<<1, 256, 0, stream>>>(hist, curs, N);
  k_scatter<<<ebl, 256, 0, stream>>>(ei, flag, ea, curs, srcS, dstS, eaS, E);
  k_node_proj<<<N, 256, 0, stream>>>(x, a, np_w, np_b, h, N);
  k_wcomb<<<24, 256, 0, stream>>>(em_w2, lin_w, wcTh, wcTl);
  k_beta<<<3, 256, 0, stream>>>(lin_w, lin_b, em_b2, beta);
  k_transp<<<dim3(4, 4, 3), 256, 0, stream>>>(m_w1, w1Th, w1Tl);
  k_transp<<<dim3(4, 4, 3), 256, 0, stream>>>(m_w2, w2Th, w2Tl);

  int n4 = N * H / 4;
  for (int l = 0; l < 3; l++) {
    k_zero<<<(n4 + 255) / 256, 256, 0, stream>>>((float4*)agg, n4);
    k_edge_mfma<<<E / TE, 512, 0, stream>>>(eaS, em_w1, em_b1,
                                            wcTh + (size_t)l * H * H,
                                            wcTl + (size_t)l * H * H,
                                            beta + (size_t)l * H,
                                            h, agg, srcS, dstS);
    k_node_mfma<<<N / 64, 256, 0, stream>>>(h, agg,
                                            w1Th + (size_t)l * H * H,
                                            m_b1 + (size_t)l * H,
                                            w2Th + (size_t)l * H * H,
                                            m_b2 + (size_t)l * H,
                                            ln_g + (size_t)l * H, ln_b + (size_t)l * H);
  }
  int g4 = B * H / 4;
  k_zero<<<(g4 + 255) / 256, 256, 0, stream>>>((float4*)g, g4);
  k_pool<<<N / 64, 256, 0, stream>>>(h, g, n);
  k_head<<<B, 256, 0, stream>>>(g, hd_w1, hd_b1, hd_w2, hd_b2, out, n);
}